// Round 2
// baseline (697.793 us; speedup 1.0000x reference)
//
#include <hip/hip_runtime.h>
#include <hip/hip_bf16.h>

#define HID 64
#define REL 5

__device__ __forceinline__ float bf2f(unsigned short u) {
    return __uint_as_float(((unsigned)u) << 16);
}
__device__ __forceinline__ unsigned short f2bf(float f) {
    __hip_bfloat16 h = (__hip_bfloat16)f;   // RNE
    return *(unsigned short*)&h;
}

// ---------------------------------------------------------------------------
// K0: runtime dtype detection.
// flags[0]: 1 if float tensors are f32, 0 if bf16.
//   W_in_b ~ U(-1/8,1/8). Under bf16 truth, even-indexed bf16-view entries are
//   real values (|v| <= 0.125). Under f32 truth they are the low mantissa bits
//   of f32 values = ~uniform 16-bit patterns: P(all 32 have |v|<=0.26) ~ 1e-10.
// flags[1]: 1 if edge_index is int64 (all odd int32 words == 0), else 0.
// ---------------------------------------------------------------------------
__global__ void k_detect(const unsigned short* __restrict__ wb,
                         const int* __restrict__ ei, int* flags) {
    if (threadIdx.x == 0) {
        float mx = 0.f;
        for (int i = 0; i < 32; i++) mx = fmaxf(mx, fabsf(bf2f(wb[2 * i])));
        flags[0] = (mx <= 0.26f) ? 0 : 1;
        int i64 = 1;
        for (int i = 0; i < 64; i++)
            if (ei[2 * i + 1] != 0) { i64 = 0; break; }
        flags[1] = i64;
    }
}

// ---------------------------------------------------------------------------
// K0b: canonicalize big float tensor (contagion_risk) -> f32
// ---------------------------------------------------------------------------
__global__ void k_cvt_big(const void* __restrict__ A, float* __restrict__ Af,
                          const int* __restrict__ flags, int n) {
    int i = blockIdx.x * 256 + threadIdx.x;
    if (i < n)
        Af[i] = flags[0] ? ((const float*)A)[i]
                         : bf2f(((const unsigned short*)A)[i]);
}

// K0c: canonicalize all weights. Win/bin/Wout/bout -> f32, Wrel -> bf16 bits.
__global__ void k_cvt_w(const void* Win, const void* bin, const void* Wr,
                        const void* Wout, const void* bout,
                        float* Winf, float* binf, unsigned short* Wrelb,
                        float* Woutf, float* boutf,
                        const int* __restrict__ flags) {
    int f = flags[0];
    int t = threadIdx.x;
    for (int i = t; i < 64 * 64; i += 256)
        Winf[i] = f ? ((const float*)Win)[i] : bf2f(((const unsigned short*)Win)[i]);
    for (int i = t; i < 64; i += 256)
        binf[i] = f ? ((const float*)bin)[i] : bf2f(((const unsigned short*)bin)[i]);
    for (int i = t; i < REL * 64 * 64; i += 256)
        Wrelb[i] = f ? f2bf(((const float*)Wr)[i]) : ((const unsigned short*)Wr)[i];
    for (int i = t; i < 64 * 64; i += 256)
        Woutf[i] = f ? ((const float*)Wout)[i] : bf2f(((const unsigned short*)Wout)[i]);
    for (int i = t; i < 64; i += 256)
        boutf[i] = f ? ((const float*)bout)[i] : bf2f(((const unsigned short*)bout)[i]);
}

// K0d: canonicalize edge_index -> rows/cols int32
__global__ void k_cvt_e(const int* __restrict__ ei, int* __restrict__ rows,
                        int* __restrict__ cols, const int* __restrict__ flags,
                        int E) {
    int e = blockIdx.x * 256 + threadIdx.x;
    if (e < E) {
        if (flags[1]) { rows[e] = ei[2 * e]; cols[e] = ei[2 * (E + e)]; }
        else          { rows[e] = ei[e];     cols[e] = ei[E + e]; }
    }
}

// ---------------------------------------------------------------------------
// K1a: x = A @ W_in + b (all f32 now). 32 nodes/block, thread=(h, 8 nodes).
// ---------------------------------------------------------------------------
__global__ void k_xin(const float* __restrict__ A, const float* __restrict__ W,
                      const float* __restrict__ b, float* __restrict__ x, int N) {
    __shared__ float Ws[64 * 64];
    __shared__ float As[32][65];
    __shared__ float bs[64];
    int tid = threadIdx.x;
    int h = tid & 63, wv = tid >> 6;
    int n0 = blockIdx.x * 32;

    for (int i = tid; i < 64 * 64; i += 256) Ws[i] = W[i];
    if (tid < 64) bs[tid] = b[tid];
    for (int i = tid; i < 32 * 64; i += 256) {
        int r = i >> 6, c = i & 63;
        As[r][c] = (n0 + r < N) ? A[(size_t)(n0 + r) * 64 + c] : 0.f;
    }
    __syncthreads();

    int nb = wv * 8;
    float acc[8];
#pragma unroll
    for (int i = 0; i < 8; i++) acc[i] = bs[h];
#pragma unroll 8
    for (int k = 0; k < 64; k++) {
        float w = Ws[k * 64 + h];
#pragma unroll
        for (int i = 0; i < 8; i++) acc[i] += As[nb + i][k] * w;
    }
#pragma unroll
    for (int i = 0; i < 8; i++) {
        int n = n0 + nb + i;
        if (n < N) x[(size_t)n * 64 + h] = acc[i];
    }
}

// ---------------------------------------------------------------------------
// K1b: Y[m] = x @ W_rel[m]; Y stored bf16 [5][N][64].
// ---------------------------------------------------------------------------
__global__ void k_y(const float* __restrict__ x,
                    const unsigned short* __restrict__ Wrb,
                    unsigned short* __restrict__ Y, int N) {
    __shared__ unsigned short Ws[REL * 64 * 64];  // 40 KB
    __shared__ float xs[32][65];
    int tid = threadIdx.x;
    int h = tid & 63, wv = tid >> 6;
    int n0 = blockIdx.x * 32;

    for (int i = tid; i < REL * 64 * 64 / 8; i += 256)
        ((uint4*)Ws)[i] = ((const uint4*)Wrb)[i];
    for (int i = tid; i < 32 * 64; i += 256) {
        int r = i >> 6, c = i & 63;
        xs[r][c] = (n0 + r < N) ? x[(size_t)(n0 + r) * 64 + c] : 0.f;
    }
    __syncthreads();

    int nb = wv * 8;
    for (int m = 0; m < REL; m++) {
        const unsigned short* wm = &Ws[m * 4096];
        float acc[8];
#pragma unroll
        for (int i = 0; i < 8; i++) acc[i] = 0.f;
#pragma unroll 8
        for (int k = 0; k < 64; k++) {
            float w = bf2f(wm[k * 64 + h]);
#pragma unroll
            for (int i = 0; i < 8; i++) acc[i] += xs[nb + i][k] * w;
        }
#pragma unroll
        for (int i = 0; i < 8; i++) {
            int n = n0 + nb + i;
            if (n < N) Y[((size_t)m * N + n) * 64 + h] = f2bf(acc[i]);
        }
    }
}

// ---------------------------------------------------------------------------
// K2: histograms over dst (sort) and src (gcn degree)
// ---------------------------------------------------------------------------
__global__ void k_hist(const int* __restrict__ rows, const int* __restrict__ cols,
                       int* cnt, int* degc, int E) {
    int e = blockIdx.x * 256 + threadIdx.x;
    if (e < E) {
        atomicAdd(&cnt[rows[e]], 1);
        atomicAdd(&degc[cols[e]], 1);
    }
}

// ---------------------------------------------------------------------------
// K3: single-block exclusive scan -> off/head; dis = deg>0 ? rsqrt(deg) : 0
// ---------------------------------------------------------------------------
__global__ void k_scan(const int* __restrict__ cnt, const int* __restrict__ degc,
                       int* off, int* head, float* dis, int N, int E) {
    __shared__ int part[256];
    int t = threadIdx.x;
    int chunk = (N + 255) / 256;
    int lo = t * chunk, hi = min(N, lo + chunk);
    int s = 0;
    for (int i = lo; i < hi; i++) s += cnt[i];
    part[t] = s;
    __syncthreads();
    if (t == 0) {
        int run = 0;
        for (int i = 0; i < 256; i++) { int v = part[i]; part[i] = run; run += v; }
    }
    __syncthreads();
    int base = part[t];
    for (int i = lo; i < hi; i++) {
        off[i] = base; head[i] = base; base += cnt[i];
        int d = degc[i];
        dis[i] = (d > 0) ? rsqrtf((float)d) : 0.f;
    }
    if (t == 0) off[N] = E;
}

// ---------------------------------------------------------------------------
// K4: scatter edges into dst-grouped order; pack col|type; precompute norm
// ---------------------------------------------------------------------------
__global__ void k_scatter(const int* __restrict__ rows, const int* __restrict__ cols,
                          const int* __restrict__ et, const float* __restrict__ dis,
                          int* head, int* spack, float* snorm, int E) {
    int e = blockIdx.x * 256 + threadIdx.x;
    if (e < E) {
        int r = rows[e], c = cols[e];
        int pos = atomicAdd(&head[r], 1);
        spack[pos] = c | (et[e] << 20);
        snorm[pos] = dis[r] * dis[c];
    }
}

// ---------------------------------------------------------------------------
// K5: one wave per dst node: online softmax + GCN + fused output GEMM.
// ---------------------------------------------------------------------------
__global__ void k_main(const float* __restrict__ x, const unsigned short* __restrict__ Y,
                       const int* __restrict__ off, const int* __restrict__ spack,
                       const float* __restrict__ snorm,
                       const float* __restrict__ Wout, const float* __restrict__ bout,
                       void* __restrict__ outv, const int* __restrict__ flags, int N) {
    __shared__ float Ws[64 * 64];
    __shared__ float vs[4][64];
    int tid = threadIdx.x;
    int h = tid & 63, wv = tid >> 6;
    int n = blockIdx.x * 4 + wv;

    for (int i = tid; i < 64 * 64; i += 256) Ws[i] = Wout[i];

    if (n < N) {
        float m = -3.0e38f, s = 0.f, num = 0.f, gcn = 0.f;
        int e0 = off[n], e1 = off[n + 1];
        for (int e = e0; e < e1; e++) {
            int pc = spack[e];           // wave-uniform
            float nw = snorm[e];         // wave-uniform
            int c = pc & 0xFFFFF, t = pc >> 20;
            float r = bf2f(Y[((size_t)t * N + (size_t)c) * 64 + h]);
            float xv = x[(size_t)c * 64 + h];
            gcn += xv * nw;
            float nm = fmaxf(m, r);
            float ea = __expf(m - nm);   // finite args always
            float eb = __expf(r - nm);
            s = s * ea + eb;
            num = num * ea + r * eb;
            m = nm;
        }
        float msg = num / (s + 1e-16f);
        vs[wv][h] = gcn + 0.5f * fmaxf(msg, 0.f);
    }
    __syncthreads();
    if (n < N) {
        float acc = bout[h];
#pragma unroll 8
        for (int k = 0; k < 64; k++) acc += vs[wv][k] * Ws[k * 64 + h];
        size_t oi = (size_t)n * 64 + h;
        if (flags[0]) ((float*)outv)[oi] = acc;
        else ((__hip_bfloat16*)outv)[oi] = (__hip_bfloat16)acc;
    }
}

// ---------------------------------------------------------------------------
extern "C" void kernel_launch(void* const* d_in, const int* in_sizes, int n_in,
                              void* d_out, int out_size, void* d_ws, size_t ws_size,
                              hipStream_t stream) {
    const void* A    = d_in[0];
    const void* Win  = d_in[2];
    const void* bin  = d_in[3];
    const void* Wrel = d_in[4];
    const void* Wout = d_in[5];
    const void* bout = d_in[6];
    const int* ei = (const int*)d_in[7];
    const int* et = (const int*)d_in[8];
    int N = in_sizes[0] / HID;   // 50000
    int E = in_sizes[8];         // 800000

    // workspace carve (4-byte words, every section multiple of 4 words)
    float* p = (float*)d_ws;
    float* xf    = p; p += (size_t)N * 64;            // 3.2M
    unsigned short* Yb = (unsigned short*)p; p += (size_t)REL * N * 64 / 2;  // 8M words
    float* Af    = p; p += (size_t)N * 64;            // 3.2M
    float* Winf  = p; p += 4096;
    float* binf  = p; p += 64;
    unsigned short* Wrelb = (unsigned short*)p; p += REL * 4096 / 2;  // 10240 words
    float* Woutf = p; p += 4096;
    float* boutf = p; p += 64;
    int* rows    = (int*)p; p += E;
    int* cols    = (int*)p; p += E;
    int* cnt     = (int*)p; p += N;
    int* degc    = (int*)p; p += N;
    int* off     = (int*)p; p += ((N + 1 + 3) / 4) * 4;
    int* head    = (int*)p; p += N;
    float* dis   = p; p += N;
    int* spack   = (int*)p; p += E;
    float* snorm = p; p += E;
    int* flags   = (int*)p; p += 4;

    hipMemsetAsync(cnt, 0, (size_t)2 * N * sizeof(int), stream);  // cnt + degc

    int nb32 = (N + 31) / 32;
    int eb   = (E + 255) / 256;
    int ab   = (N * 64 + 255) / 256;

    k_detect<<<1, 64, 0, stream>>>((const unsigned short*)bin, ei, flags);
    k_cvt_big<<<ab, 256, 0, stream>>>(A, Af, flags, N * 64);
    k_cvt_w<<<1, 256, 0, stream>>>(Win, bin, Wrel, Wout, bout,
                                   Winf, binf, Wrelb, Woutf, boutf, flags);
    k_cvt_e<<<eb, 256, 0, stream>>>(ei, rows, cols, flags, E);
    k_xin<<<nb32, 256, 0, stream>>>(Af, Winf, binf, xf, N);
    k_y<<<nb32, 256, 0, stream>>>(xf, Wrelb, Yb, N);
    k_hist<<<eb, 256, 0, stream>>>(rows, cols, cnt, degc, E);
    k_scan<<<1, 256, 0, stream>>>(cnt, degc, off, head, dis, N, E);
    k_scatter<<<eb, 256, 0, stream>>>(rows, cols, et, dis, head, spack, snorm, E);
    k_main<<<(N + 3) / 4, 256, 0, stream>>>(xf, Yb, off, spack, snorm,
                                            Woutf, boutf, d_out, flags, N);
}

// Round 3
// 468.560 us; speedup vs baseline: 1.4892x; 1.4892x over previous
//
#include <hip/hip_runtime.h>
#include <hip/hip_bf16.h>

#define HID 64
#define REL 5
#define SCAN_CHUNK 1024   // elements per scan block (256 thr x 4)

__device__ __forceinline__ float bf2f(unsigned short u) {
    return __uint_as_float(((unsigned)u) << 16);
}
__device__ __forceinline__ unsigned short f2bf(float f) {
    __hip_bfloat16 h = (__hip_bfloat16)f;   // RNE
    return *(unsigned short*)&h;
}

// ---------------------------------------------------------------------------
// K0: runtime dtype detection.
// flags[0]: 1 if float tensors are f32, 0 if bf16 (probe W_in_b ~ U(-1/8,1/8)).
// flags[1]: 1 if edge_index is int64 (all odd int32 words == 0), else 0.
// ---------------------------------------------------------------------------
__global__ void k_detect(const unsigned short* __restrict__ wb,
                         const int* __restrict__ ei, int* flags) {
    if (threadIdx.x == 0) {
        float mx = 0.f;
        for (int i = 0; i < 32; i++) mx = fmaxf(mx, fabsf(bf2f(wb[2 * i])));
        flags[0] = (mx <= 0.26f) ? 0 : 1;
        int i64 = 1;
        for (int i = 0; i < 64; i++)
            if (ei[2 * i + 1] != 0) { i64 = 0; break; }
        flags[1] = i64;
    }
}

// K0c: canonicalize weights. Win/bin/Wout/bout -> f32, Wrel -> bf16 bits.
__global__ void k_cvt_w(const void* Win, const void* bin, const void* Wr,
                        const void* Wout, const void* bout,
                        float* Winf, float* binf, unsigned short* Wrelb,
                        float* Woutf, float* boutf,
                        const int* __restrict__ flags) {
    int f = flags[0];
    int t = threadIdx.x;
    for (int i = t; i < 64 * 64; i += 256)
        Winf[i] = f ? ((const float*)Win)[i] : bf2f(((const unsigned short*)Win)[i]);
    for (int i = t; i < 64; i += 256)
        binf[i] = f ? ((const float*)bin)[i] : bf2f(((const unsigned short*)bin)[i]);
    for (int i = t; i < REL * 64 * 64; i += 256)
        Wrelb[i] = f ? f2bf(((const float*)Wr)[i]) : ((const unsigned short*)Wr)[i];
    for (int i = t; i < 64 * 64; i += 256)
        Woutf[i] = f ? ((const float*)Wout)[i] : bf2f(((const unsigned short*)Wout)[i]);
    for (int i = t; i < 64; i += 256)
        boutf[i] = f ? ((const float*)bout)[i] : bf2f(((const unsigned short*)bout)[i]);
}

// ---------------------------------------------------------------------------
// K0d+K2 fused: canonicalize edge_index -> rows/cols AND build histograms.
// ---------------------------------------------------------------------------
__global__ void k_cvt_e_hist(const int* __restrict__ ei, const int* __restrict__ flags,
                             int* __restrict__ rows, int* __restrict__ cols,
                             int* cnt, int* degc, int E) {
    int e = blockIdx.x * 256 + threadIdx.x;
    if (e < E) {
        int r, c;
        if (flags[1]) { r = ei[2 * e]; c = ei[2 * (E + e)]; }
        else          { r = ei[e];     c = ei[E + e]; }
        rows[e] = r; cols[e] = c;
        atomicAdd(&cnt[r], 1);
        atomicAdd(&degc[c], 1);
    }
}

// ---------------------------------------------------------------------------
// K1a: x = A @ W_in + b. A converted inline (f32 or bf16 per flags).
// 32 nodes/block, thread=(h, 8 nodes).
// ---------------------------------------------------------------------------
__global__ void k_xin(const void* __restrict__ A, const float* __restrict__ W,
                      const float* __restrict__ b, float* __restrict__ x,
                      const int* __restrict__ flags, int N) {
    __shared__ float Ws[64 * 64];
    __shared__ float As[32][65];
    __shared__ float bs[64];
    int tid = threadIdx.x;
    int h = tid & 63, wv = tid >> 6;
    int n0 = blockIdx.x * 32;
    int f = flags[0];

    for (int i = tid; i < 64 * 64; i += 256) Ws[i] = W[i];
    if (tid < 64) bs[tid] = b[tid];
    for (int i = tid; i < 32 * 64; i += 256) {
        int r = i >> 6, c = i & 63;
        size_t idx = (size_t)(n0 + r) * 64 + c;
        As[r][c] = (n0 + r < N)
                       ? (f ? ((const float*)A)[idx] : bf2f(((const unsigned short*)A)[idx]))
                       : 0.f;
    }
    __syncthreads();

    int nb = wv * 8;
    float acc[8];
#pragma unroll
    for (int i = 0; i < 8; i++) acc[i] = bs[h];
#pragma unroll 8
    for (int k = 0; k < 64; k++) {
        float w = Ws[k * 64 + h];
#pragma unroll
        for (int i = 0; i < 8; i++) acc[i] += As[nb + i][k] * w;
    }
#pragma unroll
    for (int i = 0; i < 8; i++) {
        int n = n0 + nb + i;
        if (n < N) x[(size_t)n * 64 + h] = acc[i];
    }
}

// ---------------------------------------------------------------------------
// K1b: Y[m] = x @ W_rel[m]; Y stored bf16 [5][N][64].
// ---------------------------------------------------------------------------
__global__ void k_y(const float* __restrict__ x,
                    const unsigned short* __restrict__ Wrb,
                    unsigned short* __restrict__ Y, int N) {
    __shared__ unsigned short Ws[REL * 64 * 64];  // 40 KB
    __shared__ float xs[32][65];
    int tid = threadIdx.x;
    int h = tid & 63, wv = tid >> 6;
    int n0 = blockIdx.x * 32;

    for (int i = tid; i < REL * 64 * 64 / 8; i += 256)
        ((uint4*)Ws)[i] = ((const uint4*)Wrb)[i];
    for (int i = tid; i < 32 * 64; i += 256) {
        int r = i >> 6, c = i & 63;
        xs[r][c] = (n0 + r < N) ? x[(size_t)(n0 + r) * 64 + c] : 0.f;
    }
    __syncthreads();

    int nb = wv * 8;
    for (int m = 0; m < REL; m++) {
        const unsigned short* wm = &Ws[m * 4096];
        float acc[8];
#pragma unroll
        for (int i = 0; i < 8; i++) acc[i] = 0.f;
#pragma unroll 8
        for (int k = 0; k < 64; k++) {
            float w = bf2f(wm[k * 64 + h]);
#pragma unroll
            for (int i = 0; i < 8; i++) acc[i] += xs[nb + i][k] * w;
        }
#pragma unroll
        for (int i = 0; i < 8; i++) {
            int n = n0 + nb + i;
            if (n < N) Y[((size_t)m * N + n) * 64 + h] = f2bf(acc[i]);
        }
    }
}

// ---------------------------------------------------------------------------
// K3a: per-block sums of cnt over SCAN_CHUNK-element chunks
// ---------------------------------------------------------------------------
__global__ void k_scan_blk(const int* __restrict__ cnt, int* __restrict__ bsum, int N) {
    __shared__ int red[256];
    int t = threadIdx.x;
    int i0 = blockIdx.x * SCAN_CHUNK + t * 4;
    int s = 0;
#pragma unroll
    for (int j = 0; j < 4; j++) { int i = i0 + j; if (i < N) s += cnt[i]; }
    red[t] = s;
    __syncthreads();
    for (int d = 128; d > 0; d >>= 1) {
        if (t < d) red[t] += red[t + d];
        __syncthreads();
    }
    if (t == 0) bsum[blockIdx.x] = red[0];
}

// K3b: exclusive scan of block sums (nsb <= 1024), one small block
__global__ void k_scan_top(int* __restrict__ bsum, int nsb) {
    __shared__ int v[1024];
    int t = threadIdx.x;
    for (int i = t; i < nsb; i += 256) v[i] = bsum[i];
    __syncthreads();
    if (t == 0) {
        int run = 0;
        for (int i = 0; i < nsb; i++) { int x = v[i]; v[i] = run; run += x; }
    }
    __syncthreads();
    for (int i = t; i < nsb; i += 256) bsum[i] = v[i];
}

// K3c: per-block exclusive scan + apply: off, head, dis
__global__ void k_scan_apply(const int* __restrict__ cnt, const int* __restrict__ degc,
                             const int* __restrict__ bsum,
                             int* off, int* head, float* dis, int N, int E) {
    __shared__ int red[256];
    int t = threadIdx.x;
    int i0 = blockIdx.x * SCAN_CHUNK + t * 4;
    int v[4];
    int s = 0;
#pragma unroll
    for (int j = 0; j < 4; j++) {
        int i = i0 + j;
        v[j] = (i < N) ? cnt[i] : 0;
        s += v[j];
    }
    red[t] = s;
    __syncthreads();
    // Hillis-Steele inclusive scan over 256 thread sums
    for (int d = 1; d < 256; d <<= 1) {
        int add = (t >= d) ? red[t - d] : 0;
        __syncthreads();
        red[t] += add;
        __syncthreads();
    }
    int run = bsum[blockIdx.x] + red[t] - s;  // exclusive base for this thread
#pragma unroll
    for (int j = 0; j < 4; j++) {
        int i = i0 + j;
        if (i < N) {
            off[i] = run; head[i] = run; run += v[j];
            int d = degc[i];
            dis[i] = (d > 0) ? rsqrtf((float)d) : 0.f;
        }
    }
    if (blockIdx.x == 0 && t == 0) off[N] = E;
}

// ---------------------------------------------------------------------------
// K4: scatter edges into dst-grouped order; pack col|type; precompute norm
// ---------------------------------------------------------------------------
__global__ void k_scatter(const int* __restrict__ rows, const int* __restrict__ cols,
                          const int* __restrict__ et, const float* __restrict__ dis,
                          int* head, int* spack, float* snorm, int E) {
    int e = blockIdx.x * 256 + threadIdx.x;
    if (e < E) {
        int r = rows[e], c = cols[e];
        int pos = atomicAdd(&head[r], 1);
        spack[pos] = c | (et[e] << 20);
        snorm[pos] = dis[r] * dis[c];
    }
}

// ---------------------------------------------------------------------------
// K5: one wave per dst node: online softmax + GCN + fused output GEMM.
// ---------------------------------------------------------------------------
__global__ void k_main(const float* __restrict__ x, const unsigned short* __restrict__ Y,
                       const int* __restrict__ off, const int* __restrict__ spack,
                       const float* __restrict__ snorm,
                       const float* __restrict__ Wout, const float* __restrict__ bout,
                       void* __restrict__ outv, const int* __restrict__ flags, int N) {
    __shared__ float Ws[64 * 64];
    __shared__ float vs[4][64];
    int tid = threadIdx.x;
    int h = tid & 63, wv = tid >> 6;
    int n = blockIdx.x * 4 + wv;

    for (int i = tid; i < 64 * 64; i += 256) Ws[i] = Wout[i];

    if (n < N) {
        float m = -3.0e38f, s = 0.f, num = 0.f, gcn = 0.f;
        int e0 = off[n], e1 = off[n + 1];
        for (int e = e0; e < e1; e++) {
            int pc = spack[e];           // wave-uniform
            float nw = snorm[e];         // wave-uniform
            int c = pc & 0xFFFFF, t = pc >> 20;
            float r = bf2f(Y[((size_t)t * N + (size_t)c) * 64 + h]);
            float xv = x[(size_t)c * 64 + h];
            gcn += xv * nw;
            float nm = fmaxf(m, r);
            float ea = __expf(m - nm);
            float eb = __expf(r - nm);
            s = s * ea + eb;
            num = num * ea + r * eb;
            m = nm;
        }
        float msg = num / (s + 1e-16f);
        vs[wv][h] = gcn + 0.5f * fmaxf(msg, 0.f);
    }
    __syncthreads();
    if (n < N) {
        float acc = bout[h];
#pragma unroll 8
        for (int k = 0; k < 64; k++) acc += vs[wv][k] * Ws[k * 64 + h];
        size_t oi = (size_t)n * 64 + h;
        if (flags[0]) ((float*)outv)[oi] = acc;
        else ((__hip_bfloat16*)outv)[oi] = (__hip_bfloat16)acc;
    }
}

// ---------------------------------------------------------------------------
extern "C" void kernel_launch(void* const* d_in, const int* in_sizes, int n_in,
                              void* d_out, int out_size, void* d_ws, size_t ws_size,
                              hipStream_t stream) {
    const void* A    = d_in[0];
    const void* Win  = d_in[2];
    const void* bin  = d_in[3];
    const void* Wrel = d_in[4];
    const void* Wout = d_in[5];
    const void* bout = d_in[6];
    const int* ei = (const int*)d_in[7];
    const int* et = (const int*)d_in[8];
    int N = in_sizes[0] / HID;   // 50000
    int E = in_sizes[8];         // 800000

    int nsb = (N + SCAN_CHUNK - 1) / SCAN_CHUNK;  // scan blocks (49)

    // workspace carve (4-byte words, sections multiple of 4 words)
    float* p = (float*)d_ws;
    float* xf    = p; p += (size_t)N * 64;
    unsigned short* Yb = (unsigned short*)p; p += (size_t)REL * N * 64 / 2;
    float* Winf  = p; p += 4096;
    float* binf  = p; p += 64;
    unsigned short* Wrelb = (unsigned short*)p; p += REL * 4096 / 2;
    float* Woutf = p; p += 4096;
    float* boutf = p; p += 64;
    int* rows    = (int*)p; p += E;
    int* cols    = (int*)p; p += E;
    int* cnt     = (int*)p; p += N;
    int* degc    = (int*)p; p += N;
    int* off     = (int*)p; p += ((N + 1 + 3) / 4) * 4;
    int* head    = (int*)p; p += N;
    float* dis   = p; p += N;
    int* spack   = (int*)p; p += E;
    float* snorm = p; p += E;
    int* bsum    = (int*)p; p += ((nsb + 3) / 4) * 4;
    int* flags   = (int*)p; p += 4;

    hipMemsetAsync(cnt, 0, (size_t)2 * N * sizeof(int), stream);  // cnt + degc

    int nb32 = (N + 31) / 32;
    int eb   = (E + 255) / 256;

    k_detect<<<1, 64, 0, stream>>>((const unsigned short*)bin, ei, flags);
    k_cvt_w<<<1, 256, 0, stream>>>(Win, bin, Wrel, Wout, bout,
                                   Winf, binf, Wrelb, Woutf, boutf, flags);
    k_cvt_e_hist<<<eb, 256, 0, stream>>>(ei, flags, rows, cols, cnt, degc, E);
    k_xin<<<nb32, 256, 0, stream>>>(A, Winf, binf, xf, flags, N);
    k_y<<<nb32, 256, 0, stream>>>(xf, Wrelb, Yb, N);
    k_scan_blk<<<nsb, 256, 0, stream>>>(cnt, bsum, N);
    k_scan_top<<<1, 256, 0, stream>>>(bsum, nsb);
    k_scan_apply<<<nsb, 256, 0, stream>>>(cnt, degc, bsum, off, head, dis, N, E);
    k_scatter<<<eb, 256, 0, stream>>>(rows, cols, et, dis, head, spack, snorm, E);
    k_main<<<(N + 3) / 4, 256, 0, stream>>>(xf, Yb, off, spack, snorm,
                                            Woutf, boutf, d_out, flags, N);
}

// Round 4
// 292.671 us; speedup vs baseline: 2.3842x; 1.6010x over previous
//
#include <hip/hip_runtime.h>
#include <hip/hip_bf16.h>

#define HID 64
#define REL 5
#define SCAN_CHUNK 1024

typedef short bf16x8 __attribute__((ext_vector_type(8)));
typedef float f32x4 __attribute__((ext_vector_type(4)));

__device__ __forceinline__ float bf2f(unsigned short u) {
    return __uint_as_float(((unsigned)u) << 16);
}
__device__ __forceinline__ unsigned short f2bf(float f) {
    __hip_bfloat16 h = (__hip_bfloat16)f;   // RNE
    return *(unsigned short*)&h;
}

// ---------------------------------------------------------------------------
// K0: dtype detection (parallel). flags[0]=1 if f32, flags[1]=1 if int64 idx.
// ---------------------------------------------------------------------------
__global__ void k_detect(const unsigned short* __restrict__ wb,
                         const int* __restrict__ ei, int* flags) {
    int lane = threadIdx.x;  // 64 threads
    bool big = (lane < 32) ? (fabsf(bf2f(wb[2 * lane])) > 0.26f) : false;
    unsigned long long b1 = __ballot(big);
    bool odd_nz = (ei[2 * lane + 1] != 0);
    unsigned long long b2 = __ballot(odd_nz);
    if (lane == 0) {
        flags[0] = (b1 != 0ull) ? 1 : 0;
        flags[1] = (b2 == 0ull) ? 1 : 0;
    }
}

// ---------------------------------------------------------------------------
// K_pack: weights -> per-lane MFMA B-fragment order, bf16.
// Bpk[mat][ks][nt][lane][j] ; mat: 0=Win, 1..5=Wrel, 6=Wout.
// frag[j] = W[32*ks + 8*(lane>>4) + j][nt*16 + (lane&15)]
// Also bin/bout -> f32.
// ---------------------------------------------------------------------------
__global__ void k_pack(const void* Win, const void* bin, const void* Wr,
                       const void* Wout, const void* bout,
                       unsigned short* __restrict__ Bpk,
                       float* __restrict__ binf, float* __restrict__ boutf,
                       const int* __restrict__ flags) {
    int f = flags[0];
    int gid = blockIdx.x * 256 + threadIdx.x;
    if (gid < 7 * 2 * 4 * 64) {
        int lane = gid & 63;
        int nt = (gid >> 6) & 3;
        int ks = (gid >> 8) & 1;
        int mat = gid >> 9;
        int q = lane >> 4, n = nt * 16 + (lane & 15);
#pragma unroll
        for (int j = 0; j < 8; j++) {
            int k = ks * 32 + q * 8 + j;
            int idx = k * 64 + n;
            float val;
            if (mat == 0)
                val = f ? ((const float*)Win)[idx] : bf2f(((const unsigned short*)Win)[idx]);
            else if (mat <= 5) {
                int ii = (mat - 1) * 4096 + idx;
                val = f ? ((const float*)Wr)[ii] : bf2f(((const unsigned short*)Wr)[ii]);
            } else
                val = f ? ((const float*)Wout)[idx] : bf2f(((const unsigned short*)Wout)[idx]);
            Bpk[(size_t)gid * 8 + j] = f2bf(val);
        }
    }
    if (gid < 64)
        binf[gid] = f ? ((const float*)bin)[gid] : bf2f(((const unsigned short*)bin)[gid]);
    else if (gid >= 64 && gid < 128) {
        int i = gid - 64;
        boutf[i] = f ? ((const float*)bout)[i] : bf2f(((const unsigned short*)bout)[i]);
    }
}

// K_cvt_big: A -> bf16 canonical (only needed when input is f32)
__global__ void k_cvt_big(const void* __restrict__ A, unsigned short* __restrict__ Ab,
                          const int* __restrict__ flags, int n) {
    if (!flags[0]) return;
    int i = blockIdx.x * 256 + threadIdx.x;
    if (i < n) Ab[i] = f2bf(((const float*)A)[i]);
}

// ---------------------------------------------------------------------------
// K_hist: degree histograms over dst (sort) and src (gcn norm)
// ---------------------------------------------------------------------------
__global__ void k_hist(const int* __restrict__ ei, const int* __restrict__ flags,
                       int* cnt, int* degc, int E) {
    int e = blockIdx.x * 256 + threadIdx.x;
    if (e < E) {
        int r, c;
        if (flags[1]) { r = ei[2 * e]; c = ei[2 * (E + e)]; }
        else          { r = ei[e];     c = ei[E + e]; }
        atomicAdd(&cnt[r], 1);
        atomicAdd(&degc[c], 1);
    }
}

// ---------------------------------------------------------------------------
// K_xy (MFMA): x = A@Win + b ; Y[r] = bf16(x)@Wrel[r]. 64 nodes/block, 4 waves.
// Yb layout [6][Np][64] bf16, slot 5 = x.
// ---------------------------------------------------------------------------
__global__ void __launch_bounds__(256)
k_xy(const void* __restrict__ A, const unsigned short* __restrict__ Ab,
     const unsigned short* __restrict__ Bpk, const float* __restrict__ binf,
     unsigned short* __restrict__ Yb, const int* __restrict__ flags,
     int N, int Np) {
    __shared__ unsigned short Bs[6 * 2 * 4 * 64 * 8];  // 48 KB
    __shared__ unsigned short Xs[64 * 64];             // 8 KB
    __shared__ float bs[64];
    int tid = threadIdx.x;
    for (int i = tid; i < 6 * 2 * 4 * 64; i += 256)
        ((uint4*)Bs)[i] = ((const uint4*)Bpk)[i];
    if (tid < 64) bs[tid] = binf[tid];
    __syncthreads();

    int w = tid >> 6, lane = tid & 63;
    int q = lane >> 4, n16 = lane & 15;
    int mrow = w * 16 + n16;                 // A-frag row within block tile
    int nodeA = blockIdx.x * 64 + mrow;
    int arow = min(nodeA, N - 1);
    const unsigned short* Asrc = flags[0] ? Ab : (const unsigned short*)A;
    bf16x8 a0 = *(const bf16x8*)(Asrc + (size_t)arow * 64 + 8 * q);
    bf16x8 a1 = *(const bf16x8*)(Asrc + (size_t)arow * 64 + 8 * q + 32);

    // stage-1: x = A @ Win + b
#pragma unroll
    for (int nt = 0; nt < 4; nt++) {
        f32x4 d = {0.f, 0.f, 0.f, 0.f};
        bf16x8 b0 = *(const bf16x8*)(Bs + (size_t)(((0 * 2 + 0) * 4 + nt) * 64 + lane) * 8);
        bf16x8 b1 = *(const bf16x8*)(Bs + (size_t)(((0 * 2 + 1) * 4 + nt) * 64 + lane) * 8);
        d = __builtin_amdgcn_mfma_f32_16x16x32_bf16(a0, b0, d, 0, 0, 0);
        d = __builtin_amdgcn_mfma_f32_16x16x32_bf16(a1, b1, d, 0, 0, 0);
        int col = nt * 16 + n16;
        float bb = bs[col];
#pragma unroll
        for (int r = 0; r < 4; r++) {
            int rowl = w * 16 + 4 * q + r;
            unsigned short hv = f2bf(d[r] + bb);
            Xs[rowl * 64 + col] = hv;
            int node = blockIdx.x * 64 + rowl;
            if (node < N) Yb[((size_t)5 * Np + node) * 64 + col] = hv;
        }
    }
    // same-wave LDS RAW (wave w wrote rows w*16..w*16+15) -> no barrier needed
    bf16x8 a20 = *(const bf16x8*)(Xs + mrow * 64 + 8 * q);
    bf16x8 a21 = *(const bf16x8*)(Xs + mrow * 64 + 8 * q + 32);

    for (int rel = 0; rel < REL; rel++) {
        int mat = 1 + rel;
#pragma unroll
        for (int nt = 0; nt < 4; nt++) {
            f32x4 d = {0.f, 0.f, 0.f, 0.f};
            bf16x8 b0 = *(const bf16x8*)(Bs + (size_t)(((mat * 2 + 0) * 4 + nt) * 64 + lane) * 8);
            bf16x8 b1 = *(const bf16x8*)(Bs + (size_t)(((mat * 2 + 1) * 4 + nt) * 64 + lane) * 8);
            d = __builtin_amdgcn_mfma_f32_16x16x32_bf16(a20, b0, d, 0, 0, 0);
            d = __builtin_amdgcn_mfma_f32_16x16x32_bf16(a21, b1, d, 0, 0, 0);
            int col = nt * 16 + n16;
#pragma unroll
            for (int r = 0; r < 4; r++) {
                int node = blockIdx.x * 64 + w * 16 + 4 * q + r;
                if (node < N) Yb[((size_t)rel * Np + node) * 64 + col] = f2bf(d[r]);
            }
        }
    }
}

// ---------------------------------------------------------------------------
// Scan trio (unchanged from r3)
// ---------------------------------------------------------------------------
__global__ void k_scan_blk(const int* __restrict__ cnt, int* __restrict__ bsum, int N) {
    __shared__ int red[256];
    int t = threadIdx.x;
    int i0 = blockIdx.x * SCAN_CHUNK + t * 4;
    int s = 0;
#pragma unroll
    for (int j = 0; j < 4; j++) { int i = i0 + j; if (i < N) s += cnt[i]; }
    red[t] = s;
    __syncthreads();
    for (int d = 128; d > 0; d >>= 1) {
        if (t < d) red[t] += red[t + d];
        __syncthreads();
    }
    if (t == 0) bsum[blockIdx.x] = red[0];
}

__global__ void k_scan_top(int* __restrict__ bsum, int nsb) {
    __shared__ int v[1024];
    int t = threadIdx.x;
    for (int i = t; i < nsb; i += 256) v[i] = bsum[i];
    __syncthreads();
    if (t == 0) {
        int run = 0;
        for (int i = 0; i < nsb; i++) { int x = v[i]; v[i] = run; run += x; }
    }
    __syncthreads();
    for (int i = t; i < nsb; i += 256) bsum[i] = v[i];
}

__global__ void k_scan_apply(const int* __restrict__ cnt, const int* __restrict__ degc,
                             const int* __restrict__ bsum,
                             int* off, int* head, float* dis, int N, int E) {
    __shared__ int red[256];
    int t = threadIdx.x;
    int i0 = blockIdx.x * SCAN_CHUNK + t * 4;
    int v[4];
    int s = 0;
#pragma unroll
    for (int j = 0; j < 4; j++) {
        int i = i0 + j;
        v[j] = (i < N) ? cnt[i] : 0;
        s += v[j];
    }
    red[t] = s;
    __syncthreads();
    for (int d = 1; d < 256; d <<= 1) {
        int add = (t >= d) ? red[t - d] : 0;
        __syncthreads();
        red[t] += add;
        __syncthreads();
    }
    int run = bsum[blockIdx.x] + red[t] - s;
#pragma unroll
    for (int j = 0; j < 4; j++) {
        int i = i0 + j;
        if (i < N) {
            off[i] = run; head[i] = run; run += v[j];
            int d = degc[i];
            dis[i] = (d > 0) ? rsqrtf((float)d) : 0.f;
        }
    }
    if (blockIdx.x == 0 && t == 0) off[N] = E;
}

// ---------------------------------------------------------------------------
// K_scatter: dst-grouped edge records: {col|type<<20, norm bits} as one uint2
// ---------------------------------------------------------------------------
__global__ void k_scatter(const int* __restrict__ ei, const int* __restrict__ et,
                          const int* __restrict__ flags, const float* __restrict__ dis,
                          int* head, uint2* __restrict__ edata, int E) {
    int e = blockIdx.x * 256 + threadIdx.x;
    if (e < E) {
        int r, c;
        if (flags[1]) { r = ei[2 * e]; c = ei[2 * (E + e)]; }
        else          { r = ei[e];     c = ei[E + e]; }
        int t = et[e];
        int pos = atomicAdd(&head[r], 1);
        edata[pos] = make_uint2((unsigned)c | ((unsigned)t << 20),
                                __float_as_uint(dis[r] * dis[c]));
    }
}

// ---------------------------------------------------------------------------
// K_main: one node per wave; 2 half-waves process alternate edges; lane = 2 ch.
// Associative softmax sums (no max chain; exp arg bounded by data, guard 60).
// v[n] = gcn + 0.5*relu(num/(s+1e-16))  -> bf16
// ---------------------------------------------------------------------------
__global__ void __launch_bounds__(256)
k_main(const unsigned short* __restrict__ Yb, const int* __restrict__ off,
       const uint2* __restrict__ edata, unsigned short* __restrict__ v,
       int N, int Np) {
    int tid = threadIdx.x;
    int wv = tid >> 6, lane = tid & 63;
    int n = blockIdx.x * 4 + wv;
    if (n >= N) return;
    int half = lane >> 5;
    int c2 = (lane & 31) * 2;
    int e0 = off[n], e1 = off[n + 1];
    float s0 = 0.f, s1 = 0.f, u0 = 0.f, u1 = 0.f, g0 = 0.f, g1 = 0.f;
    const unsigned short* Yx = Yb + (size_t)5 * Np * 64;
    for (int e = e0 + half; e < e1; e += 2) {
        uint2 md = edata[e];
        float nw = __uint_as_float(md.y);
        int c = md.x & 0xFFFFF;
        int t = md.x >> 20;
        unsigned yv = *(const unsigned*)(Yb + ((size_t)t * Np + c) * 64 + c2);
        unsigned xv = *(const unsigned*)(Yx + (size_t)c * 64 + c2);
        float r0 = __uint_as_float(yv << 16);
        float r1 = __uint_as_float(yv & 0xFFFF0000u);
        float x0 = __uint_as_float(xv << 16);
        float x1 = __uint_as_float(xv & 0xFFFF0000u);
        g0 += x0 * nw; g1 += x1 * nw;
        float p0 = __expf(fminf(r0, 60.f));
        float p1 = __expf(fminf(r1, 60.f));
        s0 += p0; s1 += p1;
        u0 += r0 * p0; u1 += r1 * p1;
    }
    s0 += __shfl_xor(s0, 32); s1 += __shfl_xor(s1, 32);
    u0 += __shfl_xor(u0, 32); u1 += __shfl_xor(u1, 32);
    g0 += __shfl_xor(g0, 32); g1 += __shfl_xor(g1, 32);
    if (half == 0) {
        float m0 = u0 / (s0 + 1e-16f), m1 = u1 / (s1 + 1e-16f);
        float v0 = g0 + 0.5f * fmaxf(m0, 0.f);
        float v1 = g1 + 0.5f * fmaxf(m1, 0.f);
        unsigned pack = (unsigned)f2bf(v0) | ((unsigned)f2bf(v1) << 16);
        *(unsigned*)(v + (size_t)n * 64 + c2) = pack;
    }
}

// ---------------------------------------------------------------------------
// K_out (MFMA): out = v @ Wout + bout. 64 nodes/block.
// ---------------------------------------------------------------------------
__global__ void __launch_bounds__(256)
k_out(const unsigned short* __restrict__ v, const unsigned short* __restrict__ Bpk,
      const float* __restrict__ boutf, void* __restrict__ outv,
      const int* __restrict__ flags, int N, int Np) {
    __shared__ unsigned short Bs[2 * 4 * 64 * 8];  // 8 KB (mat 6)
    __shared__ float bs[64];
    int tid = threadIdx.x;
    const unsigned short* src = Bpk + (size_t)6 * 2 * 4 * 64 * 8;
    for (int i = tid; i < 2 * 4 * 64; i += 256)
        ((uint4*)Bs)[i] = ((const uint4*)src)[i];
    if (tid < 64) bs[tid] = boutf[tid];
    __syncthreads();

    int w = tid >> 6, lane = tid & 63;
    int q = lane >> 4, n16 = lane & 15;
    int arow = min(blockIdx.x * 64 + w * 16 + n16, N - 1);
    bf16x8 a0 = *(const bf16x8*)(v + (size_t)arow * 64 + 8 * q);
    bf16x8 a1 = *(const bf16x8*)(v + (size_t)arow * 64 + 8 * q + 32);
    int f = flags[0];
#pragma unroll
    for (int nt = 0; nt < 4; nt++) {
        f32x4 d = {0.f, 0.f, 0.f, 0.f};
        bf16x8 b0 = *(const bf16x8*)(Bs + (size_t)((0 * 4 + nt) * 64 + lane) * 8);
        bf16x8 b1 = *(const bf16x8*)(Bs + (size_t)((1 * 4 + nt) * 64 + lane) * 8);
        d = __builtin_amdgcn_mfma_f32_16x16x32_bf16(a0, b0, d, 0, 0, 0);
        d = __builtin_amdgcn_mfma_f32_16x16x32_bf16(a1, b1, d, 0, 0, 0);
        int col = nt * 16 + n16;
        float bb = bs[col];
#pragma unroll
        for (int r = 0; r < 4; r++) {
            int node = blockIdx.x * 64 + w * 16 + 4 * q + r;
            if (node < N) {
                float o = d[r] + bb;
                if (f) ((float*)outv)[(size_t)node * 64 + col] = o;
                else   ((unsigned short*)outv)[(size_t)node * 64 + col] = f2bf(o);
            }
        }
    }
}

// ---------------------------------------------------------------------------
extern "C" void kernel_launch(void* const* d_in, const int* in_sizes, int n_in,
                              void* d_out, int out_size, void* d_ws, size_t ws_size,
                              hipStream_t stream) {
    const void* A    = d_in[0];
    const void* Win  = d_in[2];
    const void* bin  = d_in[3];
    const void* Wrel = d_in[4];
    const void* Wout = d_in[5];
    const void* bout = d_in[6];
    const int* ei = (const int*)d_in[7];
    const int* et = (const int*)d_in[8];
    int N = in_sizes[0] / HID;          // 50000
    int E = in_sizes[8];                // 800000
    int Np = ((N + 63) / 64) * 64;      // 50048
    int nsb = (N + SCAN_CHUNK - 1) / SCAN_CHUNK;

    // workspace carve (keep every section 16B-aligned)
    char* p = (char*)d_ws;
    auto carve = [&](size_t bytes) {
        char* q = p;
        p += (bytes + 15) & ~(size_t)15;
        return q;
    };
    unsigned short* Yb   = (unsigned short*)carve((size_t)6 * Np * 64 * 2);  // 38.4 MB
    unsigned short* vv   = (unsigned short*)carve((size_t)Np * 64 * 2);      // 6.4 MB
    unsigned short* Ab   = (unsigned short*)carve((size_t)Np * 64 * 2);      // 6.4 MB
    uint2*          edata= (uint2*)carve((size_t)E * 8);                     // 6.4 MB
    unsigned short* Bpk  = (unsigned short*)carve((size_t)7 * 4096 * 2);
    float* binf  = (float*)carve(64 * 4);
    float* boutf = (float*)carve(64 * 4);
    int* cnt     = (int*)carve((size_t)N * 4);
    int* degc    = (int*)carve((size_t)N * 4);
    int* off     = (int*)carve((size_t)(N + 1) * 4);
    int* head    = (int*)carve((size_t)N * 4);
    float* dis   = (float*)carve((size_t)N * 4);
    int* bsum    = (int*)carve((size_t)nsb * 4);
    int* flags   = (int*)carve(16);

    hipMemsetAsync(cnt, 0, (size_t)2 * N * sizeof(int), stream);  // cnt + degc

    int eb = (E + 255) / 256;
    int ab = (N * 64 + 255) / 256;
    int nb64 = Np / 64;

    k_detect<<<1, 64, 0, stream>>>((const unsigned short*)bin, ei, flags);
    k_pack<<<14, 256, 0, stream>>>(Win, bin, Wrel, Wout, bout, Bpk, binf, boutf, flags);
    k_cvt_big<<<ab, 256, 0, stream>>>(A, Ab, flags, N * 64);
    k_hist<<<eb, 256, 0, stream>>>(ei, flags, cnt, degc, E);
    k_xy<<<nb64, 256, 0, stream>>>(A, Ab, Bpk, binf, Yb, flags, N, Np);
    k_scan_blk<<<nsb, 256, 0, stream>>>(cnt, bsum, N);
    k_scan_top<<<1, 256, 0, stream>>>(bsum, nsb);
    k_scan_apply<<<nsb, 256, 0, stream>>>(cnt, degc, bsum, off, head, dis, N, E);
    k_scatter<<<eb, 256, 0, stream>>>(ei, et, flags, dis, head, edata, E);
    k_main<<<(N + 3) / 4, 256, 0, stream>>>(Yb, off, edata, vv, N, Np);
    k_out<<<nb64, 256, 0, stream>>>(vv, Bpk, boutf, d_out, flags, N, Np);
}

// Round 5
// 265.479 us; speedup vs baseline: 2.6284x; 1.1024x over previous
//
#include <hip/hip_runtime.h>
#include <hip/hip_bf16.h>

#define HID 64
#define REL 5
#define SCAN_CHUNK 1024

typedef short bf16x8 __attribute__((ext_vector_type(8)));
typedef float f32x4 __attribute__((ext_vector_type(4)));

__device__ __forceinline__ float bf2f(unsigned short u) {
    return __uint_as_float(((unsigned)u) << 16);
}
__device__ __forceinline__ unsigned short f2bf(float f) {
    __hip_bfloat16 h = (__hip_bfloat16)f;   // RNE
    return *(unsigned short*)&h;
}

// ---------------------------------------------------------------------------
// K0: dtype detection (parallel). flags[0]=1 if f32, flags[1]=1 if int64 idx.
// ---------------------------------------------------------------------------
__global__ void k_detect(const unsigned short* __restrict__ wb,
                         const int* __restrict__ ei, int* flags) {
    int lane = threadIdx.x;  // 64 threads
    bool big = (lane < 32) ? (fabsf(bf2f(wb[2 * lane])) > 0.26f) : false;
    unsigned long long b1 = __ballot(big);
    bool odd_nz = (ei[2 * lane + 1] != 0);
    unsigned long long b2 = __ballot(odd_nz);
    if (lane == 0) {
        flags[0] = (b1 != 0ull) ? 1 : 0;
        flags[1] = (b2 == 0ull) ? 1 : 0;
    }
}

// ---------------------------------------------------------------------------
// K_pack: weights -> per-lane MFMA B-fragment order, bf16.
// Bpk[mat][ks][nt][lane][j] ; mat: 0=Win, 1..5=Wrel, 6=Wout.
// frag[j] = W[32*ks + 8*(lane>>4) + j][nt*16 + (lane&15)]
// ---------------------------------------------------------------------------
__global__ void k_pack(const void* Win, const void* bin, const void* Wr,
                       const void* Wout, const void* bout,
                       unsigned short* __restrict__ Bpk,
                       float* __restrict__ binf, float* __restrict__ boutf,
                       const int* __restrict__ flags) {
    int f = flags[0];
    int gid = blockIdx.x * 256 + threadIdx.x;
    if (gid < 7 * 2 * 4 * 64) {
        int lane = gid & 63;
        int nt = (gid >> 6) & 3;
        int ks = (gid >> 8) & 1;
        int mat = gid >> 9;
        int q = lane >> 4, n = nt * 16 + (lane & 15);
#pragma unroll
        for (int j = 0; j < 8; j++) {
            int k = ks * 32 + q * 8 + j;
            int idx = k * 64 + n;
            float val;
            if (mat == 0)
                val = f ? ((const float*)Win)[idx] : bf2f(((const unsigned short*)Win)[idx]);
            else if (mat <= 5) {
                int ii = (mat - 1) * 4096 + idx;
                val = f ? ((const float*)Wr)[ii] : bf2f(((const unsigned short*)Wr)[ii]);
            } else
                val = f ? ((const float*)Wout)[idx] : bf2f(((const unsigned short*)Wout)[idx]);
            Bpk[(size_t)gid * 8 + j] = f2bf(val);
        }
    }
    if (gid < 64)
        binf[gid] = f ? ((const float*)bin)[gid] : bf2f(((const unsigned short*)bin)[gid]);
    else if (gid >= 64 && gid < 128) {
        int i = gid - 64;
        boutf[i] = f ? ((const float*)bout)[i] : bf2f(((const unsigned short*)bout)[i]);
    }
}

// ---------------------------------------------------------------------------
// K_hist_rank: decode edges once; histograms + in-segment rank.
//   ec[e] = c | t<<20 ; er[e] = r ; rank[e] = old cnt[r] ; degc[c]++
// ---------------------------------------------------------------------------
__global__ void k_hist_rank(const int* __restrict__ ei, const int* __restrict__ et,
                            const int* __restrict__ flags,
                            unsigned* __restrict__ ec, int* __restrict__ er,
                            int* __restrict__ rank, int* cnt, int* degc, int E) {
    int e = blockIdx.x * 256 + threadIdx.x;
    if (e < E) {
        int r, c;
        if (flags[1]) { r = ei[2 * e]; c = ei[2 * (E + e)]; }
        else          { r = ei[e];     c = ei[E + e]; }
        ec[e] = (unsigned)c | ((unsigned)et[e] << 20);
        er[e] = r;
        rank[e] = atomicAdd(&cnt[r], 1);
        atomicAdd(&degc[c], 1);
    }
}

// ---------------------------------------------------------------------------
// Scan trio: cnt -> off (exclusive); dis = deg>0 ? rsqrt(deg) : 0
// ---------------------------------------------------------------------------
__global__ void k_scan_blk(const int* __restrict__ cnt, int* __restrict__ bsum, int N) {
    __shared__ int red[256];
    int t = threadIdx.x;
    int i0 = blockIdx.x * SCAN_CHUNK + t * 4;
    int s = 0;
#pragma unroll
    for (int j = 0; j < 4; j++) { int i = i0 + j; if (i < N) s += cnt[i]; }
    red[t] = s;
    __syncthreads();
    for (int d = 128; d > 0; d >>= 1) {
        if (t < d) red[t] += red[t + d];
        __syncthreads();
    }
    if (t == 0) bsum[blockIdx.x] = red[0];
}

__global__ void k_scan_top(int* __restrict__ bsum, int nsb) {
    __shared__ int v[1024];
    int t = threadIdx.x;
    for (int i = t; i < nsb; i += 256) v[i] = bsum[i];
    __syncthreads();
    if (t == 0) {
        int run = 0;
        for (int i = 0; i < nsb; i++) { int x = v[i]; v[i] = run; run += x; }
    }
    __syncthreads();
    for (int i = t; i < nsb; i += 256) bsum[i] = v[i];
}

__global__ void k_scan_apply(const int* __restrict__ cnt, const int* __restrict__ degc,
                             const int* __restrict__ bsum,
                             int* off, float* dis, int N, int E) {
    __shared__ int red[256];
    int t = threadIdx.x;
    int i0 = blockIdx.x * SCAN_CHUNK + t * 4;
    int v[4];
    int s = 0;
#pragma unroll
    for (int j = 0; j < 4; j++) {
        int i = i0 + j;
        v[j] = (i < N) ? cnt[i] : 0;
        s += v[j];
    }
    red[t] = s;
    __syncthreads();
    for (int d = 1; d < 256; d <<= 1) {
        int add = (t >= d) ? red[t - d] : 0;
        __syncthreads();
        red[t] += add;
        __syncthreads();
    }
    int run = bsum[blockIdx.x] + red[t] - s;
#pragma unroll
    for (int j = 0; j < 4; j++) {
        int i = i0 + j;
        if (i < N) {
            off[i] = run; run += v[j];
            int d = degc[i];
            dis[i] = (d > 0) ? rsqrtf((float)d) : 0.f;
        }
    }
    if (blockIdx.x == 0 && t == 0) off[N] = E;
}

// ---------------------------------------------------------------------------
// K_xy (MFMA): x = A@Win + b ; Y[r] = bf16(x)@Wrel[r].
// Yb layout [6][Np][64] bf16; slot 5 = x * dis[node] (pre-scaled for GCN).
// ---------------------------------------------------------------------------
__device__ __forceinline__ bf16x8 load_a8(const void* A, int f, size_t base) {
    if (f) {
        const float* Af = (const float*)A + base;
        bf16x8 r;
#pragma unroll
        for (int j = 0; j < 8; j++) r[j] = (short)f2bf(Af[j]);
        return r;
    }
    return *(const bf16x8*)((const unsigned short*)A + base);
}

__global__ void __launch_bounds__(256)
k_xy(const void* __restrict__ A, const unsigned short* __restrict__ Bpk,
     const float* __restrict__ binf, const float* __restrict__ dis,
     unsigned short* __restrict__ Yb, const int* __restrict__ flags,
     int N, int Np) {
    __shared__ unsigned short Bs[6 * 2 * 4 * 64 * 8];  // 48 KB
    __shared__ unsigned short Xs[64 * 64];             // 8 KB
    __shared__ float bs[64];
    int tid = threadIdx.x;
    for (int i = tid; i < 6 * 2 * 4 * 64; i += 256)
        ((uint4*)Bs)[i] = ((const uint4*)Bpk)[i];
    if (tid < 64) bs[tid] = binf[tid];
    __syncthreads();

    int w = tid >> 6, lane = tid & 63;
    int q = lane >> 4, n16 = lane & 15;
    int mrow = w * 16 + n16;
    int f = flags[0];
    int arow = min(blockIdx.x * 64 + mrow, N - 1);
    bf16x8 a0 = load_a8(A, f, (size_t)arow * 64 + 8 * q);
    bf16x8 a1 = load_a8(A, f, (size_t)arow * 64 + 8 * q + 32);

    // dis for the 4 accumulator rows of this lane (same rows for every nt)
    float disv[4];
#pragma unroll
    for (int r = 0; r < 4; r++) {
        int node = blockIdx.x * 64 + w * 16 + 4 * q + r;
        disv[r] = (node < N) ? dis[node] : 0.f;
    }

    // stage-1: x = A @ Win + b ; slot5 = x * dis
#pragma unroll
    for (int nt = 0; nt < 4; nt++) {
        f32x4 d = {0.f, 0.f, 0.f, 0.f};
        bf16x8 b0 = *(const bf16x8*)(Bs + (size_t)(((0 * 2 + 0) * 4 + nt) * 64 + lane) * 8);
        bf16x8 b1 = *(const bf16x8*)(Bs + (size_t)(((0 * 2 + 1) * 4 + nt) * 64 + lane) * 8);
        d = __builtin_amdgcn_mfma_f32_16x16x32_bf16(a0, b0, d, 0, 0, 0);
        d = __builtin_amdgcn_mfma_f32_16x16x32_bf16(a1, b1, d, 0, 0, 0);
        int col = nt * 16 + n16;
        float bb = bs[col];
#pragma unroll
        for (int r = 0; r < 4; r++) {
            int rowl = w * 16 + 4 * q + r;
            float xval = d[r] + bb;
            Xs[rowl * 64 + col] = f2bf(xval);
            int node = blockIdx.x * 64 + rowl;
            if (node < N) Yb[((size_t)5 * Np + node) * 64 + col] = f2bf(xval * disv[r]);
        }
    }
    // same-wave LDS RAW (wave w wrote rows w*16..w*16+15) -> no barrier needed
    bf16x8 a20 = *(const bf16x8*)(Xs + mrow * 64 + 8 * q);
    bf16x8 a21 = *(const bf16x8*)(Xs + mrow * 64 + 8 * q + 32);

    for (int rel = 0; rel < REL; rel++) {
        int mat = 1 + rel;
#pragma unroll
        for (int nt = 0; nt < 4; nt++) {
            f32x4 d = {0.f, 0.f, 0.f, 0.f};
            bf16x8 b0 = *(const bf16x8*)(Bs + (size_t)(((mat * 2 + 0) * 4 + nt) * 64 + lane) * 8);
            bf16x8 b1 = *(const bf16x8*)(Bs + (size_t)(((mat * 2 + 1) * 4 + nt) * 64 + lane) * 8);
            d = __builtin_amdgcn_mfma_f32_16x16x32_bf16(a20, b0, d, 0, 0, 0);
            d = __builtin_amdgcn_mfma_f32_16x16x32_bf16(a21, b1, d, 0, 0, 0);
            int col = nt * 16 + n16;
#pragma unroll
            for (int r = 0; r < 4; r++) {
                int node = blockIdx.x * 64 + w * 16 + 4 * q + r;
                if (node < N) Yb[((size_t)rel * Np + node) * 64 + col] = f2bf(d[r]);
            }
        }
    }
}

// ---------------------------------------------------------------------------
// K_scatter: atomic-free — pos = off[r] + rank[e]; edata4[pos] = c|t<<20
// ---------------------------------------------------------------------------
__global__ void k_scatter(const unsigned* __restrict__ ec, const int* __restrict__ er,
                          const int* __restrict__ rank, const int* __restrict__ off,
                          unsigned* __restrict__ edata4, int E) {
    int e = blockIdx.x * 256 + threadIdx.x;
    if (e < E) {
        int pos = off[er[e]] + rank[e];
        edata4[pos] = ec[e];
    }
}

// ---------------------------------------------------------------------------
// K_main: one node per wave; 2 half-waves split edges; lane = 2 channels.
// gcn = dis[n] * sum(xs[c]); softmax sums associative (no max chain).
// ---------------------------------------------------------------------------
__global__ void __launch_bounds__(256)
k_main(const unsigned short* __restrict__ Yb, const int* __restrict__ off,
       const unsigned* __restrict__ edata4, const float* __restrict__ dis,
       unsigned short* __restrict__ v, int N, int Np) {
    int tid = threadIdx.x;
    int wv = tid >> 6, lane = tid & 63;
    int n = blockIdx.x * 4 + wv;
    if (n >= N) return;
    int half = lane >> 5;
    int c2 = (lane & 31) * 2;
    int e0 = off[n], e1 = off[n + 1];
    float s0 = 0.f, s1 = 0.f, u0 = 0.f, u1 = 0.f, g0 = 0.f, g1 = 0.f;
    const unsigned short* Yx = Yb + (size_t)5 * Np * 64;
    for (int e = e0 + half; e < e1; e += 2) {
        unsigned md = edata4[e];        // wave-uniform scalar load
        int c = md & 0xFFFFF;
        int t = md >> 20;
        unsigned yv = *(const unsigned*)(Yb + ((size_t)t * Np + c) * 64 + c2);
        unsigned xv = *(const unsigned*)(Yx + (size_t)c * 64 + c2);
        float r0 = __uint_as_float(yv << 16);
        float r1 = __uint_as_float(yv & 0xFFFF0000u);
        g0 += __uint_as_float(xv << 16);
        g1 += __uint_as_float(xv & 0xFFFF0000u);
        float p0 = __expf(fminf(r0, 60.f));
        float p1 = __expf(fminf(r1, 60.f));
        s0 += p0; s1 += p1;
        u0 += r0 * p0; u1 += r1 * p1;
    }
    s0 += __shfl_xor(s0, 32); s1 += __shfl_xor(s1, 32);
    u0 += __shfl_xor(u0, 32); u1 += __shfl_xor(u1, 32);
    g0 += __shfl_xor(g0, 32); g1 += __shfl_xor(g1, 32);
    if (half == 0) {
        float dn = dis[n];
        float m0 = u0 / (s0 + 1e-16f), m1 = u1 / (s1 + 1e-16f);
        float v0 = g0 * dn + 0.5f * fmaxf(m0, 0.f);
        float v1 = g1 * dn + 0.5f * fmaxf(m1, 0.f);
        unsigned pack = (unsigned)f2bf(v0) | ((unsigned)f2bf(v1) << 16);
        *(unsigned*)(v + (size_t)n * 64 + c2) = pack;
    }
}

// ---------------------------------------------------------------------------
// K_out (MFMA): out = v @ Wout + bout. 64 nodes/block.
// ---------------------------------------------------------------------------
__global__ void __launch_bounds__(256)
k_out(const unsigned short* __restrict__ v, const unsigned short* __restrict__ Bpk,
      const float* __restrict__ boutf, void* __restrict__ outv,
      const int* __restrict__ flags, int N, int Np) {
    __shared__ unsigned short Bs[2 * 4 * 64 * 8];  // 8 KB (mat 6)
    __shared__ float bs[64];
    int tid = threadIdx.x;
    const unsigned short* src = Bpk + (size_t)6 * 2 * 4 * 64 * 8;
    for (int i = tid; i < 2 * 4 * 64; i += 256)
        ((uint4*)Bs)[i] = ((const uint4*)src)[i];
    if (tid < 64) bs[tid] = boutf[tid];
    __syncthreads();

    int w = tid >> 6, lane = tid & 63;
    int q = lane >> 4, n16 = lane & 15;
    int arow = min(blockIdx.x * 64 + w * 16 + n16, N - 1);
    bf16x8 a0 = *(const bf16x8*)(v + (size_t)arow * 64 + 8 * q);
    bf16x8 a1 = *(const bf16x8*)(v + (size_t)arow * 64 + 8 * q + 32);
    int f = flags[0];
#pragma unroll
    for (int nt = 0; nt < 4; nt++) {
        f32x4 d = {0.f, 0.f, 0.f, 0.f};
        bf16x8 b0 = *(const bf16x8*)(Bs + (size_t)((0 * 4 + nt) * 64 + lane) * 8);
        bf16x8 b1 = *(const bf16x8*)(Bs + (size_t)((1 * 4 + nt) * 64 + lane) * 8);
        d = __builtin_amdgcn_mfma_f32_16x16x32_bf16(a0, b0, d, 0, 0, 0);
        d = __builtin_amdgcn_mfma_f32_16x16x32_bf16(a1, b1, d, 0, 0, 0);
        int col = nt * 16 + n16;
        float bb = bs[col];
#pragma unroll
        for (int r = 0; r < 4; r++) {
            int node = blockIdx.x * 64 + w * 16 + 4 * q + r;
            if (node < N) {
                float o = d[r] + bb;
                if (f) ((float*)outv)[(size_t)node * 64 + col] = o;
                else   ((unsigned short*)outv)[(size_t)node * 64 + col] = f2bf(o);
            }
        }
    }
}

// ---------------------------------------------------------------------------
extern "C" void kernel_launch(void* const* d_in, const int* in_sizes, int n_in,
                              void* d_out, int out_size, void* d_ws, size_t ws_size,
                              hipStream_t stream) {
    const void* A    = d_in[0];
    const void* Win  = d_in[2];
    const void* bin  = d_in[3];
    const void* Wrel = d_in[4];
    const void* Wout = d_in[5];
    const void* bout = d_in[6];
    const int* ei = (const int*)d_in[7];
    const int* et = (const int*)d_in[8];
    int N = in_sizes[0] / HID;          // 50000
    int E = in_sizes[8];                // 800000
    int Np = ((N + 63) / 64) * 64;      // 50048
    int nsb = (N + SCAN_CHUNK - 1) / SCAN_CHUNK;

    char* p = (char*)d_ws;
    auto carve = [&](size_t bytes) {
        char* q = p;
        p += (bytes + 15) & ~(size_t)15;
        return q;
    };
    unsigned short* Yb   = (unsigned short*)carve((size_t)6 * Np * 64 * 2);  // 38.4 MB
    unsigned short* vv   = (unsigned short*)carve((size_t)Np * 64 * 2);      // 6.4 MB
    unsigned*       ec   = (unsigned*)carve((size_t)E * 4);
    int*            er   = (int*)carve((size_t)E * 4);
    int*            rank = (int*)carve((size_t)E * 4);
    unsigned*       edata4 = (unsigned*)carve((size_t)E * 4);
    unsigned short* Bpk  = (unsigned short*)carve((size_t)7 * 4096 * 2);
    float* binf  = (float*)carve(64 * 4);
    float* boutf = (float*)carve(64 * 4);
    int* cnt     = (int*)carve((size_t)N * 4);
    int* degc    = (int*)carve((size_t)N * 4);   // contiguous with cnt (N*4 % 16 == 0)
    int* off     = (int*)carve((size_t)(N + 1) * 4);
    float* dis   = (float*)carve((size_t)N * 4);
    int* bsum    = (int*)carve((size_t)nsb * 4);
    int* flags   = (int*)carve(16);

    hipMemsetAsync(cnt, 0, (size_t)2 * N * sizeof(int), stream);  // cnt + degc

    int eb = (E + 255) / 256;
    int nb64 = Np / 64;

    k_detect<<<1, 64, 0, stream>>>((const unsigned short*)bin, ei, flags);
    k_pack<<<14, 256, 0, stream>>>(Win, bin, Wrel, Wout, bout, Bpk, binf, boutf, flags);
    k_hist_rank<<<eb, 256, 0, stream>>>(ei, et, flags, ec, er, rank, cnt, degc, E);
    k_scan_blk<<<nsb, 256, 0, stream>>>(cnt, bsum, N);
    k_scan_top<<<1, 256, 0, stream>>>(bsum, nsb);
    k_scan_apply<<<nsb, 256, 0, stream>>>(cnt, degc, bsum, off, dis, N, E);
    k_xy<<<nb64, 256, 0, stream>>>(A, Bpk, binf, dis, Yb, flags, N, Np);
    k_scatter<<<eb, 256, 0, stream>>>(ec, er, rank, off, edata4, E);
    k_main<<<(N + 3) / 4, 256, 0, stream>>>(Yb, off, edata4, dis, vv, N, Np);
    k_out<<<nb64, 256, 0, stream>>>(vv, Bpk, boutf, d_out, flags, N, Np);
}

// Round 7
// 232.110 us; speedup vs baseline: 3.0063x; 1.1438x over previous
//
#include <hip/hip_runtime.h>
#include <hip/hip_bf16.h>

#define HID 64
#define REL 5
#define EPB 2048          // edges per partition block (8/thread * 256)

typedef short bf16x8 __attribute__((ext_vector_type(8)));
typedef float f32x4 __attribute__((ext_vector_type(4)));

__device__ __forceinline__ float bf2f(unsigned short u) {
    return __uint_as_float(((unsigned)u) << 16);
}
__device__ __forceinline__ unsigned short f2bf(float f) {
    __hip_bfloat16 h = (__hip_bfloat16)f;   // RNE
    return *(unsigned short*)&h;
}
__device__ __forceinline__ void dec_edge(const int* __restrict__ ei, int i64,
                                         int E, int e, int& r, int& c) {
    if (i64) { r = ei[2 * e]; c = ei[2 * (E + e)]; }
    else     { r = ei[e];     c = ei[E + e]; }
}

// ---------------------------------------------------------------------------
// K0: dtype detection. flags[0]=1 if f32, flags[1]=1 if int64 edge_index.
// ---------------------------------------------------------------------------
__global__ void k_detect(const unsigned short* __restrict__ wb,
                         const int* __restrict__ ei, int* flags) {
    int lane = threadIdx.x;  // 64 threads
    bool big = (lane < 32) ? (fabsf(bf2f(wb[2 * lane])) > 0.26f) : false;
    unsigned long long b1 = __ballot(big);
    bool odd_nz = (ei[2 * lane + 1] != 0);
    unsigned long long b2 = __ballot(odd_nz);
    if (lane == 0) {
        flags[0] = (b1 != 0ull) ? 1 : 0;
        flags[1] = (b2 == 0ull) ? 1 : 0;
    }
}

// ---------------------------------------------------------------------------
// K_pack: weights -> per-lane MFMA B-fragment order, bf16.
// Bpk[mat][ks][nt][lane][j]; mat: 0=Win, 1..5=Wrel, 6=Wout.
// frag[j] = W[32*ks + 8*(lane>>4) + j][nt*16 + (lane&15)]
// ---------------------------------------------------------------------------
__global__ void k_pack(const void* Win, const void* bin, const void* Wr,
                       const void* Wout, const void* bout,
                       unsigned short* __restrict__ Bpk,
                       float* __restrict__ binf, float* __restrict__ boutf,
                       const int* __restrict__ flags) {
    int f = flags[0];
    int gid = blockIdx.x * 256 + threadIdx.x;
    if (gid < 7 * 2 * 4 * 64) {
        int lane = gid & 63;
        int nt = (gid >> 6) & 3;
        int ks = (gid >> 8) & 1;
        int mat = gid >> 9;
        int q = lane >> 4, n = nt * 16 + (lane & 15);
#pragma unroll
        for (int j = 0; j < 8; j++) {
            int k = ks * 32 + q * 8 + j;
            int idx = k * 64 + n;
            float val;
            if (mat == 0)
                val = f ? ((const float*)Win)[idx] : bf2f(((const unsigned short*)Win)[idx]);
            else if (mat <= 5) {
                int ii = (mat - 1) * 4096 + idx;
                val = f ? ((const float*)Wr)[ii] : bf2f(((const unsigned short*)Wr)[ii]);
            } else
                val = f ? ((const float*)Wout)[idx] : bf2f(((const unsigned short*)Wout)[idx]);
            Bpk[(size_t)gid * 8 + j] = f2bf(val);
        }
    }
    if (gid < 64)
        binf[gid] = f ? ((const float*)bin)[gid] : bf2f(((const unsigned short*)bin)[gid]);
    else if (gid >= 64 && gid < 128) {
        int i = gid - 64;
        boutf[i] = f ? ((const float*)bout)[i] : bf2f(((const unsigned short*)bout)[i]);
    }
}

// ---------------------------------------------------------------------------
// P1a: per-block LDS histograms of r>>6 and c>>6.
// hist layout: [bin*nblk + blk] for R, then +NB*nblk for C. LDS atomics only.
// ---------------------------------------------------------------------------
__global__ void k_p1a(const int* __restrict__ ei, const int* __restrict__ flags,
                      int* __restrict__ hist, int E, int NB, int nblk) {
    extern __shared__ int lh[];  // 2*NB
    int tid = threadIdx.x, blk = blockIdx.x;
    for (int i = tid; i < 2 * NB; i += 256) lh[i] = 0;
    __syncthreads();
    int i64 = flags[1];
#pragma unroll
    for (int k = 0; k < EPB / 256; k++) {
        int e = blk * EPB + k * 256 + tid;
        if (e < E) {
            int r, c;
            dec_edge(ei, i64, E, e, r, c);
            atomicAdd(&lh[r >> 6], 1);
            atomicAdd(&lh[NB + (c >> 6)], 1);
        }
    }
    __syncthreads();
    size_t NBn = (size_t)NB * nblk;
    for (int i = tid; i < NB; i += 256) {
        hist[(size_t)i * nblk + blk] = lh[i];
        hist[NBn + (size_t)i * nblk + blk] = lh[NB + i];
    }
}

// ---------------------------------------------------------------------------
// Generic exclusive scan over M ints (in-place), 3 kernels, CHUNK=1024.
// ---------------------------------------------------------------------------
__global__ void s_blk(const int* __restrict__ v, int* __restrict__ bsum, int M) {
    __shared__ int red[256];
    int t = threadIdx.x;
    int i0 = blockIdx.x * 1024 + t * 4;
    int s = 0;
#pragma unroll
    for (int j = 0; j < 4; j++) { int i = i0 + j; if (i < M) s += v[i]; }
    red[t] = s;
    __syncthreads();
    for (int d = 128; d > 0; d >>= 1) {
        if (t < d) red[t] += red[t + d];
        __syncthreads();
    }
    if (t == 0) bsum[blockIdx.x] = red[0];
}

__global__ void s_top(int* __restrict__ bsum, int nsb) {
    __shared__ int v[1024];
    int t = threadIdx.x;
    for (int i = t; i < nsb; i += 256) v[i] = bsum[i];
    __syncthreads();
    if (t == 0) {
        int run = 0;
        for (int i = 0; i < nsb; i++) { int x = v[i]; v[i] = run; run += x; }
    }
    __syncthreads();
    for (int i = t; i < nsb; i += 256) bsum[i] = v[i];
}

__global__ void s_apply(int* __restrict__ v, const int* __restrict__ bsum, int M) {
    __shared__ int red[256];
    int t = threadIdx.x;
    int i0 = blockIdx.x * 1024 + t * 4;
    int x[4];
    int s = 0;
#pragma unroll
    for (int j = 0; j < 4; j++) {
        int i = i0 + j;
        x[j] = (i < M) ? v[i] : 0;
        s += x[j];
    }
    red[t] = s;
    __syncthreads();
    for (int d = 1; d < 256; d <<= 1) {
        int add = (t >= d) ? red[t - d] : 0;
        __syncthreads();
        red[t] += add;
        __syncthreads();
    }
    int run = bsum[blockIdx.x] + red[t] - s;
#pragma unroll
    for (int j = 0; j < 4; j++) {
        int i = i0 + j;
        if (i < M) { int tmp = x[j]; v[i] = run; run += tmp; }
    }
}

// ---------------------------------------------------------------------------
// P1c: partition. rbuf[posR] = rlow<<26 | t<<17 | c ; cb8[posC] = c&63.
// pos = scanned hist base + LDS rank. No global atomics.
// ---------------------------------------------------------------------------
__global__ void k_p1c(const int* __restrict__ ei, const int* __restrict__ et,
                      const int* __restrict__ flags, const int* __restrict__ hist,
                      unsigned* __restrict__ rbuf, unsigned char* __restrict__ cb8,
                      int E, int NB, int nblk) {
    extern __shared__ int lh[];  // 2*NB rank counters
    int tid = threadIdx.x, blk = blockIdx.x;
    for (int i = tid; i < 2 * NB; i += 256) lh[i] = 0;
    __syncthreads();
    int i64 = flags[1];
    size_t NBn = (size_t)NB * nblk;
#pragma unroll
    for (int k = 0; k < EPB / 256; k++) {
        int e = blk * EPB + k * 256 + tid;
        if (e < E) {
            int r, c;
            dec_edge(ei, i64, E, e, r, c);
            int t = et[e];
            int binR = r >> 6;
            int posR = hist[(size_t)binR * nblk + blk] + atomicAdd(&lh[binR], 1);
            rbuf[posR] = ((unsigned)(r & 63) << 26) | ((unsigned)t << 17) | (unsigned)c;
            int binC = c >> 6;
            int posC = hist[NBn + (size_t)binC * nblk + blk] - E + atomicAdd(&lh[NB + binC], 1);
            cb8[posC] = (unsigned char)(c & 63);
        }
    }
}

// ---------------------------------------------------------------------------
// P2r: one block per r-bucket (64 nodes): LDS hist -> off[] + final edata4.
// ---------------------------------------------------------------------------
__global__ void k_p2r(const unsigned* __restrict__ rbuf, const int* __restrict__ hist,
                      int* __restrict__ off, unsigned* __restrict__ edata4,
                      int E, int N, int NB, int nblk) {
    __shared__ int lcnt[64], excl[64], lcnt2[64];
    int tid = threadIdx.x, bk = blockIdx.x;
    int bstart = hist[(size_t)bk * nblk];
    int bend = (bk + 1 < NB) ? hist[(size_t)(bk + 1) * nblk] : E;
    if (tid < 64) { lcnt[tid] = 0; lcnt2[tid] = 0; }
    __syncthreads();
    for (int e = bstart + tid; e < bend; e += 256)
        atomicAdd(&lcnt[rbuf[e] >> 26], 1);
    __syncthreads();
    if (tid == 0) {
        int run = 0;
        for (int j = 0; j < 64; j++) { excl[j] = run; run += lcnt[j]; }
    }
    __syncthreads();
    if (tid < 64) {
        int node = bk * 64 + tid;
        if (node < N) off[node] = bstart + excl[tid];
    }
    if (bk == 0 && tid == 0) off[N] = E;
    for (int e = bstart + tid; e < bend; e += 256) {
        unsigned rec = rbuf[e];
        int rl = rec >> 26;
        int t = (rec >> 17) & 7;
        int c = rec & 0x1FFFF;
        int pos = bstart + excl[rl] + atomicAdd(&lcnt2[rl], 1);
        edata4[pos] = (unsigned)c | ((unsigned)t << 20);
    }
}

// ---------------------------------------------------------------------------
// P2c: one block per c-bucket: LDS hist of c&63 -> dis[] directly.
// ---------------------------------------------------------------------------
__global__ void k_p2c(const unsigned char* __restrict__ cb8, const int* __restrict__ hist,
                      float* __restrict__ dis, int E, int N, int NB, int nblk) {
    __shared__ int lcnt[64];
    int tid = threadIdx.x, bk = blockIdx.x;
    size_t NBn = (size_t)NB * nblk;
    int cstart = hist[NBn + (size_t)bk * nblk] - E;
    int cend = (bk + 1 < NB) ? hist[NBn + (size_t)(bk + 1) * nblk] - E : E;
    if (tid < 64) lcnt[tid] = 0;
    __syncthreads();
    for (int e = cstart + tid; e < cend; e += 256)
        atomicAdd(&lcnt[cb8[e]], 1);
    __syncthreads();
    if (tid < 64) {
        int node = bk * 64 + tid;
        if (node < N) {
            int d = lcnt[tid];
            dis[node] = (d > 0) ? rsqrtf((float)d) : 0.f;
        }
    }
}

// ---------------------------------------------------------------------------
// K_xy (MFMA): x = A@Win + b ; Y[r] = bf16(x)@Wrel[r].
// Yb layout [6][Np][64] bf16; slot 5 = x * dis[node] (pre-scaled for GCN).
// ---------------------------------------------------------------------------
__device__ __forceinline__ bf16x8 load_a8(const void* A, int f, size_t base) {
    if (f) {
        const float* Af = (const float*)A + base;
        bf16x8 r;
#pragma unroll
        for (int j = 0; j < 8; j++) r[j] = (short)f2bf(Af[j]);
        return r;
    }
    return *(const bf16x8*)((const unsigned short*)A + base);
}

__global__ void __launch_bounds__(256)
k_xy(const void* __restrict__ A, const unsigned short* __restrict__ Bpk,
     const float* __restrict__ binf, const float* __restrict__ dis,
     unsigned short* __restrict__ Yb, const int* __restrict__ flags,
     int N, int Np) {
    __shared__ unsigned short Bs[6 * 2 * 4 * 64 * 8];  // 48 KB
    __shared__ unsigned short Xs[64 * 64];             // 8 KB
    __shared__ float bs[64];
    int tid = threadIdx.x;
    for (int i = tid; i < 6 * 2 * 4 * 64; i += 256)
        ((uint4*)Bs)[i] = ((const uint4*)Bpk)[i];
    if (tid < 64) bs[tid] = binf[tid];
    __syncthreads();

    int w = tid >> 6, lane = tid & 63;
    int q = lane >> 4, n16 = lane & 15;
    int mrow = w * 16 + n16;
    int f = flags[0];
    int arow = min(blockIdx.x * 64 + mrow, N - 1);
    bf16x8 a0 = load_a8(A, f, (size_t)arow * 64 + 8 * q);
    bf16x8 a1 = load_a8(A, f, (size_t)arow * 64 + 8 * q + 32);

    float disv[4];
#pragma unroll
    for (int r = 0; r < 4; r++) {
        int node = blockIdx.x * 64 + w * 16 + 4 * q + r;
        disv[r] = (node < N) ? dis[node] : 0.f;
    }

    // stage-1: x = A @ Win + b ; slot5 = x * dis
#pragma unroll
    for (int nt = 0; nt < 4; nt++) {
        f32x4 d = {0.f, 0.f, 0.f, 0.f};
        bf16x8 b0 = *(const bf16x8*)(Bs + (size_t)(((0 * 2 + 0) * 4 + nt) * 64 + lane) * 8);
        bf16x8 b1 = *(const bf16x8*)(Bs + (size_t)(((0 * 2 + 1) * 4 + nt) * 64 + lane) * 8);
        d = __builtin_amdgcn_mfma_f32_16x16x32_bf16(a0, b0, d, 0, 0, 0);
        d = __builtin_amdgcn_mfma_f32_16x16x32_bf16(a1, b1, d, 0, 0, 0);
        int col = nt * 16 + n16;
        float bb = bs[col];
#pragma unroll
        for (int r = 0; r < 4; r++) {
            int rowl = w * 16 + 4 * q + r;
            float xval = d[r] + bb;
            Xs[rowl * 64 + col] = f2bf(xval);
            int node = blockIdx.x * 64 + rowl;
            if (node < N) Yb[((size_t)5 * Np + node) * 64 + col] = f2bf(xval * disv[r]);
        }
    }
    // same-wave LDS RAW (wave w wrote rows w*16..w*16+15) -> no barrier needed
    bf16x8 a20 = *(const bf16x8*)(Xs + mrow * 64 + 8 * q);
    bf16x8 a21 = *(const bf16x8*)(Xs + mrow * 64 + 8 * q + 32);

    for (int rel = 0; rel < REL; rel++) {
        int mat = 1 + rel;
#pragma unroll
        for (int nt = 0; nt < 4; nt++) {
            f32x4 d = {0.f, 0.f, 0.f, 0.f};
            bf16x8 b0 = *(const bf16x8*)(Bs + (size_t)(((mat * 2 + 0) * 4 + nt) * 64 + lane) * 8);
            bf16x8 b1 = *(const bf16x8*)(Bs + (size_t)(((mat * 2 + 1) * 4 + nt) * 64 + lane) * 8);
            d = __builtin_amdgcn_mfma_f32_16x16x32_bf16(a20, b0, d, 0, 0, 0);
            d = __builtin_amdgcn_mfma_f32_16x16x32_bf16(a21, b1, d, 0, 0, 0);
            int col = nt * 16 + n16;
#pragma unroll
            for (int r = 0; r < 4; r++) {
                int node = blockIdx.x * 64 + w * 16 + 4 * q + r;
                if (node < N) Yb[((size_t)rel * Np + node) * 64 + col] = f2bf(d[r]);
            }
        }
    }
}

// ---------------------------------------------------------------------------
// K_main: one node per wave; 2 half-waves split edges; lane = 2 channels.
// ---------------------------------------------------------------------------
__global__ void __launch_bounds__(256)
k_main(const unsigned short* __restrict__ Yb, const int* __restrict__ off,
       const unsigned* __restrict__ edata4, const float* __restrict__ dis,
       unsigned short* __restrict__ v, int N, int Np) {
    int tid = threadIdx.x;
    int wv = tid >> 6, lane = tid & 63;
    int n = blockIdx.x * 4 + wv;
    if (n >= N) return;
    int half = lane >> 5;
    int c2 = (lane & 31) * 2;
    int e0 = off[n], e1 = off[n + 1];
    float s0 = 0.f, s1 = 0.f, u0 = 0.f, u1 = 0.f, g0 = 0.f, g1 = 0.f;
    const unsigned short* Yx = Yb + (size_t)5 * Np * 64;
    for (int e = e0 + half; e < e1; e += 2) {
        unsigned md = edata4[e];
        int c = md & 0xFFFFF;
        int t = md >> 20;
        unsigned yv = *(const unsigned*)(Yb + ((size_t)t * Np + c) * 64 + c2);
        unsigned xv = *(const unsigned*)(Yx + (size_t)c * 64 + c2);
        float r0 = __uint_as_float(yv << 16);
        float r1 = __uint_as_float(yv & 0xFFFF0000u);
        g0 += __uint_as_float(xv << 16);
        g1 += __uint_as_float(xv & 0xFFFF0000u);
        float p0 = __expf(fminf(r0, 60.f));
        float p1 = __expf(fminf(r1, 60.f));
        s0 += p0; s1 += p1;
        u0 += r0 * p0; u1 += r1 * p1;
    }
    s0 += __shfl_xor(s0, 32); s1 += __shfl_xor(s1, 32);
    u0 += __shfl_xor(u0, 32); u1 += __shfl_xor(u1, 32);
    g0 += __shfl_xor(g0, 32); g1 += __shfl_xor(g1, 32);
    if (half == 0) {
        float dn = dis[n];
        float m0 = u0 / (s0 + 1e-16f), m1 = u1 / (s1 + 1e-16f);
        float v0 = g0 * dn + 0.5f * fmaxf(m0, 0.f);
        float v1 = g1 * dn + 0.5f * fmaxf(m1, 0.f);
        unsigned pack = (unsigned)f2bf(v0) | ((unsigned)f2bf(v1) << 16);
        *(unsigned*)(v + (size_t)n * 64 + c2) = pack;
    }
}

// ---------------------------------------------------------------------------
// K_out (MFMA): out = v @ Wout + bout.
// ---------------------------------------------------------------------------
__global__ void __launch_bounds__(256)
k_out(const unsigned short* __restrict__ v, const unsigned short* __restrict__ Bpk,
      const float* __restrict__ boutf, void* __restrict__ outv,
      const int* __restrict__ flags, int N, int Np) {
    __shared__ unsigned short Bs[2 * 4 * 64 * 8];  // 8 KB (mat 6)
    __shared__ float bs[64];
    int tid = threadIdx.x;
    const unsigned short* src = Bpk + (size_t)6 * 2 * 4 * 64 * 8;
    for (int i = tid; i < 2 * 4 * 64; i += 256)
        ((uint4*)Bs)[i] = ((const uint4*)src)[i];
    if (tid < 64) bs[tid] = boutf[tid];
    __syncthreads();

    int w = tid >> 6, lane = tid & 63;
    int q = lane >> 4, n16 = lane & 15;
    int arow = min(blockIdx.x * 64 + w * 16 + n16, N - 1);
    bf16x8 a0 = *(const bf16x8*)(v + (size_t)arow * 64 + 8 * q);
    bf16x8 a1 = *(const bf16x8*)(v + (size_t)arow * 64 + 8 * q + 32);
    int f = flags[0];
#pragma unroll
    for (int nt = 0; nt < 4; nt++) {
        f32x4 d = {0.f, 0.f, 0.f, 0.f};
        bf16x8 b0 = *(const bf16x8*)(Bs + (size_t)((0 * 4 + nt) * 64 + lane) * 8);
        bf16x8 b1 = *(const bf16x8*)(Bs + (size_t)((1 * 4 + nt) * 64 + lane) * 8);
        d = __builtin_amdgcn_mfma_f32_16x16x32_bf16(a0, b0, d, 0, 0, 0);
        d = __builtin_amdgcn_mfma_f32_16x16x32_bf16(a1, b1, d, 0, 0, 0);
        int col = nt * 16 + n16;
        float bb = bs[col];
#pragma unroll
        for (int r = 0; r < 4; r++) {
            int node = blockIdx.x * 64 + w * 16 + 4 * q + r;
            if (node < N) {
                float o = d[r] + bb;
                if (f) ((float*)outv)[(size_t)node * 64 + col] = o;
                else   ((unsigned short*)outv)[(size_t)node * 64 + col] = f2bf(o);
            }
        }
    }
}

// ---------------------------------------------------------------------------
extern "C" void kernel_launch(void* const* d_in, const int* in_sizes, int n_in,
                              void* d_out, int out_size, void* d_ws, size_t ws_size,
                              hipStream_t stream) {
    const void* A    = d_in[0];
    const void* Win  = d_in[2];
    const void* bin  = d_in[3];
    const void* Wrel = d_in[4];
    const void* Wout = d_in[5];
    const void* bout = d_in[6];
    const int* ei = (const int*)d_in[7];
    const int* et = (const int*)d_in[8];
    int N = in_sizes[0] / HID;          // 50000
    int E = in_sizes[8];                // 800000
    int Np = ((N + 63) / 64) * 64;      // 50048
    int NB = Np / 64;                   // 782 buckets of 64 nodes
    int nblk = (E + EPB - 1) / EPB;     // 391 partition blocks
    int M = 2 * NB * nblk;              // concatenated hist length
    int nsb = (M + 1023) / 1024;        // scan blocks (<=1024 required)

    char* p = (char*)d_ws;
    auto carve = [&](size_t bytes) {
        char* q = p;
        p += (bytes + 15) & ~(size_t)15;
        return q;
    };
    unsigned short* Yb   = (unsigned short*)carve((size_t)6 * Np * 64 * 2);  // 38.4 MB
    unsigned short* vv   = (unsigned short*)carve((size_t)Np * 64 * 2);      // 6.4 MB
    unsigned*       rbuf = (unsigned*)carve((size_t)E * 4);                  // 3.2 MB
    unsigned char*  cb8  = (unsigned char*)carve((size_t)E);                 // 0.8 MB
    unsigned*       edata4 = (unsigned*)carve((size_t)E * 4);                // 3.2 MB
    int*            hist = (int*)carve((size_t)M * 4);                       // 2.45 MB
    unsigned short* Bpk  = (unsigned short*)carve((size_t)7 * 4096 * 2);
    float* binf  = (float*)carve(64 * 4);
    float* boutf = (float*)carve(64 * 4);
    int* off     = (int*)carve((size_t)(N + 1) * 4);
    float* dis   = (float*)carve((size_t)N * 4);
    int* bsum    = (int*)carve((size_t)nsb * 4);
    int* flags   = (int*)carve(16);

    size_t lds_part = (size_t)2 * NB * 4;  // 6.3 KB dynamic LDS

    k_detect<<<1, 64, 0, stream>>>((const unsigned short*)bin, ei, flags);
    k_pack<<<14, 256, 0, stream>>>(Win, bin, Wrel, Wout, bout, Bpk, binf, boutf, flags);
    k_p1a<<<nblk, 256, lds_part, stream>>>(ei, flags, hist, E, NB, nblk);
    s_blk<<<nsb, 256, 0, stream>>>(hist, bsum, M);
    s_top<<<1, 256, 0, stream>>>(bsum, nsb);
    s_apply<<<nsb, 256, 0, stream>>>(hist, bsum, M);
    k_p1c<<<nblk, 256, lds_part, stream>>>(ei, et, flags, hist, rbuf, cb8, E, NB, nblk);
    k_p2r<<<NB, 256, 0, stream>>>(rbuf, hist, off, edata4, E, N, NB, nblk);
    k_p2c<<<NB, 256, 0, stream>>>(cb8, hist, dis, E, N, NB, nblk);
    k_xy<<<Np / 64, 256, 0, stream>>>(A, Bpk, binf, dis, Yb, flags, N, Np);
    k_main<<<(N + 3) / 4, 256, 0, stream>>>(Yb, off, edata4, dis, vv, N, Np);
    k_out<<<Np / 64, 256, 0, stream>>>(vv, Bpk, boutf, d_out, flags, N, Np);
}

// Round 8
// 215.429 us; speedup vs baseline: 3.2391x; 1.0774x over previous
//
#include <hip/hip_runtime.h>
#include <hip/hip_bf16.h>

#define HID 64
#define REL 5
#define EPB 2048          // edges per partition block (8/thread * 256)

typedef short bf16x8 __attribute__((ext_vector_type(8)));
typedef float f32x4 __attribute__((ext_vector_type(4)));

__device__ __forceinline__ float bf2f(unsigned short u) {
    return __uint_as_float(((unsigned)u) << 16);
}
__device__ __forceinline__ unsigned short f2bf(float f) {
    __hip_bfloat16 h = (__hip_bfloat16)f;   // RNE
    return *(unsigned short*)&h;
}
__device__ __forceinline__ void dec_edge(const int* __restrict__ ei, int i64,
                                         int E, int e, int& r, int& c) {
    if (i64) { r = ei[2 * e]; c = ei[2 * (E + e)]; }
    else     { r = ei[e];     c = ei[E + e]; }
}

// ---------------------------------------------------------------------------
// K0: dtype detection. flags[0]=1 if f32, flags[1]=1 if int64 edge_index.
// ---------------------------------------------------------------------------
__global__ void k_detect(const unsigned short* __restrict__ wb,
                         const int* __restrict__ ei, int* flags) {
    int lane = threadIdx.x;  // 64 threads
    bool big = (lane < 32) ? (fabsf(bf2f(wb[2 * lane])) > 0.26f) : false;
    unsigned long long b1 = __ballot(big);
    bool odd_nz = (ei[2 * lane + 1] != 0);
    unsigned long long b2 = __ballot(odd_nz);
    if (lane == 0) {
        flags[0] = (b1 != 0ull) ? 1 : 0;
        flags[1] = (b2 == 0ull) ? 1 : 0;
    }
}

// ---------------------------------------------------------------------------
// K_pack: weights -> per-lane MFMA B-fragment order, bf16.
// Bpk[mat][ks][nt][lane][j]; mat: 0=Win, 1..5=Wrel, 6=Wout.
// frag[j] = W[32*ks + 8*(lane>>4) + j][nt*16 + (lane&15)]
// ---------------------------------------------------------------------------
__global__ void k_pack(const void* Win, const void* bin, const void* Wr,
                       const void* Wout, const void* bout,
                       unsigned short* __restrict__ Bpk,
                       float* __restrict__ binf, float* __restrict__ boutf,
                       const int* __restrict__ flags) {
    int f = flags[0];
    int gid = blockIdx.x * 256 + threadIdx.x;
    if (gid < 7 * 2 * 4 * 64) {
        int lane = gid & 63;
        int nt = (gid >> 6) & 3;
        int ks = (gid >> 8) & 1;
        int mat = gid >> 9;
        int q = lane >> 4, n = nt * 16 + (lane & 15);
#pragma unroll
        for (int j = 0; j < 8; j++) {
            int k = ks * 32 + q * 8 + j;
            int idx = k * 64 + n;
            float val;
            if (mat == 0)
                val = f ? ((const float*)Win)[idx] : bf2f(((const unsigned short*)Win)[idx]);
            else if (mat <= 5) {
                int ii = (mat - 1) * 4096 + idx;
                val = f ? ((const float*)Wr)[ii] : bf2f(((const unsigned short*)Wr)[ii]);
            } else
                val = f ? ((const float*)Wout)[idx] : bf2f(((const unsigned short*)Wout)[idx]);
            Bpk[(size_t)gid * 8 + j] = f2bf(val);
        }
    }
    if (gid < 64)
        binf[gid] = f ? ((const float*)bin)[gid] : bf2f(((const unsigned short*)bin)[gid]);
    else if (gid >= 64 && gid < 128) {
        int i = gid - 64;
        boutf[i] = f ? ((const float*)bout)[i] : bf2f(((const unsigned short*)bout)[i]);
    }
}

// ---------------------------------------------------------------------------
// P1a: per-block LDS histograms of r>>6 and c>>6.
// ---------------------------------------------------------------------------
__global__ void k_p1a(const int* __restrict__ ei, const int* __restrict__ flags,
                      int* __restrict__ hist, int E, int NB, int nblk) {
    extern __shared__ int lh[];  // 2*NB
    int tid = threadIdx.x, blk = blockIdx.x;
    for (int i = tid; i < 2 * NB; i += 256) lh[i] = 0;
    __syncthreads();
    int i64 = flags[1];
#pragma unroll
    for (int k = 0; k < EPB / 256; k++) {
        int e = blk * EPB + k * 256 + tid;
        if (e < E) {
            int r, c;
            dec_edge(ei, i64, E, e, r, c);
            atomicAdd(&lh[r >> 6], 1);
            atomicAdd(&lh[NB + (c >> 6)], 1);
        }
    }
    __syncthreads();
    size_t NBn = (size_t)NB * nblk;
    for (int i = tid; i < NB; i += 256) {
        hist[(size_t)i * nblk + blk] = lh[i];
        hist[NBn + (size_t)i * nblk + blk] = lh[NB + i];
    }
}

// ---------------------------------------------------------------------------
// Generic exclusive scan over M ints (in-place), 3 kernels, CHUNK=1024.
// ---------------------------------------------------------------------------
__global__ void s_blk(const int* __restrict__ v, int* __restrict__ bsum, int M) {
    __shared__ int red[256];
    int t = threadIdx.x;
    int i0 = blockIdx.x * 1024 + t * 4;
    int s = 0;
#pragma unroll
    for (int j = 0; j < 4; j++) { int i = i0 + j; if (i < M) s += v[i]; }
    red[t] = s;
    __syncthreads();
    for (int d = 128; d > 0; d >>= 1) {
        if (t < d) red[t] += red[t + d];
        __syncthreads();
    }
    if (t == 0) bsum[blockIdx.x] = red[0];
}

__global__ void s_top(int* __restrict__ bsum, int nsb) {
    __shared__ int v[1024];
    int t = threadIdx.x;
    for (int i = t; i < nsb; i += 256) v[i] = bsum[i];
    __syncthreads();
    if (t == 0) {
        int run = 0;
        for (int i = 0; i < nsb; i++) { int x = v[i]; v[i] = run; run += x; }
    }
    __syncthreads();
    for (int i = t; i < nsb; i += 256) bsum[i] = v[i];
}

__global__ void s_apply(int* __restrict__ v, const int* __restrict__ bsum, int M) {
    __shared__ int red[256];
    int t = threadIdx.x;
    int i0 = blockIdx.x * 1024 + t * 4;
    int x[4];
    int s = 0;
#pragma unroll
    for (int j = 0; j < 4; j++) {
        int i = i0 + j;
        x[j] = (i < M) ? v[i] : 0;
        s += x[j];
    }
    red[t] = s;
    __syncthreads();
    for (int d = 1; d < 256; d <<= 1) {
        int add = (t >= d) ? red[t - d] : 0;
        __syncthreads();
        red[t] += add;
        __syncthreads();
    }
    int run = bsum[blockIdx.x] + red[t] - s;
#pragma unroll
    for (int j = 0; j < 4; j++) {
        int i = i0 + j;
        if (i < M) { int tmp = x[j]; v[i] = run; run += tmp; }
    }
}

// ---------------------------------------------------------------------------
// P1c: partition. rbuf[posR] = rlow<<26 | t<<17 | c ; cb8[posC] = c&63.
// ---------------------------------------------------------------------------
__global__ void k_p1c(const int* __restrict__ ei, const int* __restrict__ et,
                      const int* __restrict__ flags, const int* __restrict__ hist,
                      unsigned* __restrict__ rbuf, unsigned char* __restrict__ cb8,
                      int E, int NB, int nblk) {
    extern __shared__ int lh[];  // 2*NB rank counters
    int tid = threadIdx.x, blk = blockIdx.x;
    for (int i = tid; i < 2 * NB; i += 256) lh[i] = 0;
    __syncthreads();
    int i64 = flags[1];
    size_t NBn = (size_t)NB * nblk;
#pragma unroll
    for (int k = 0; k < EPB / 256; k++) {
        int e = blk * EPB + k * 256 + tid;
        if (e < E) {
            int r, c;
            dec_edge(ei, i64, E, e, r, c);
            int t = et[e];
            int binR = r >> 6;
            int posR = hist[(size_t)binR * nblk + blk] + atomicAdd(&lh[binR], 1);
            rbuf[posR] = ((unsigned)(r & 63) << 26) | ((unsigned)t << 17) | (unsigned)c;
            int binC = c >> 6;
            int posC = hist[NBn + (size_t)binC * nblk + blk] - E + atomicAdd(&lh[NB + binC], 1);
            cb8[posC] = (unsigned char)(c & 63);
        }
    }
}

// ---------------------------------------------------------------------------
// P2r: one block per r-bucket (64 nodes): LDS hist -> off[] + final edata4.
// ---------------------------------------------------------------------------
__global__ void k_p2r(const unsigned* __restrict__ rbuf, const int* __restrict__ hist,
                      int* __restrict__ off, unsigned* __restrict__ edata4,
                      int E, int N, int NB, int nblk) {
    __shared__ int lcnt[64], excl[64], lcnt2[64];
    int tid = threadIdx.x, bk = blockIdx.x;
    int bstart = hist[(size_t)bk * nblk];
    int bend = (bk + 1 < NB) ? hist[(size_t)(bk + 1) * nblk] : E;
    if (tid < 64) { lcnt[tid] = 0; lcnt2[tid] = 0; }
    __syncthreads();
    for (int e = bstart + tid; e < bend; e += 256)
        atomicAdd(&lcnt[rbuf[e] >> 26], 1);
    __syncthreads();
    if (tid == 0) {
        int run = 0;
        for (int j = 0; j < 64; j++) { excl[j] = run; run += lcnt[j]; }
    }
    __syncthreads();
    if (tid < 64) {
        int node = bk * 64 + tid;
        if (node < N) off[node] = bstart + excl[tid];
    }
    if (bk == 0 && tid == 0) off[N] = E;
    for (int e = bstart + tid; e < bend; e += 256) {
        unsigned rec = rbuf[e];
        int rl = rec >> 26;
        int t = (rec >> 17) & 7;
        int c = rec & 0x1FFFF;
        int pos = bstart + excl[rl] + atomicAdd(&lcnt2[rl], 1);
        edata4[pos] = (unsigned)c | ((unsigned)t << 20);
    }
}

// ---------------------------------------------------------------------------
// P2c: one block per c-bucket: LDS hist of c&63 -> dis[] (all Np, padding=0).
// ---------------------------------------------------------------------------
__global__ void k_p2c(const unsigned char* __restrict__ cb8, const int* __restrict__ hist,
                      float* __restrict__ dis, int E, int NB, int nblk) {
    __shared__ int lcnt[64];
    int tid = threadIdx.x, bk = blockIdx.x;
    size_t NBn = (size_t)NB * nblk;
    int cstart = hist[NBn + (size_t)bk * nblk] - E;
    int cend = (bk + 1 < NB) ? hist[NBn + (size_t)(bk + 1) * nblk] - E : E;
    if (tid < 64) lcnt[tid] = 0;
    __syncthreads();
    for (int e = cstart + tid; e < cend; e += 256)
        atomicAdd(&lcnt[cb8[e]], 1);
    __syncthreads();
    if (tid < 64) {
        int node = bk * 64 + tid;
        int d = lcnt[tid];
        dis[node] = (d > 0) ? rsqrtf((float)d) : 0.f;   // padding nodes -> 0
    }
}

// ---------------------------------------------------------------------------
// K_xy (MFMA): x = A@Win + b ; Y[r] = bf16(x)@Wrel[r].
// Yb layout [6][Np][64] bf16; slot 5 = x * dis[node] (pre-scaled for GCN).
// Epilogue: LDS transpose -> bf16x8 vector stores (no scalar 2B stores).
// ---------------------------------------------------------------------------
__device__ __forceinline__ bf16x8 load_a8(const void* A, int f, size_t base) {
    if (f) {
        const float* Af = (const float*)A + base;
        bf16x8 r;
#pragma unroll
        for (int j = 0; j < 8; j++) r[j] = (short)f2bf(Af[j]);
        return r;
    }
    return *(const bf16x8*)((const unsigned short*)A + base);
}

__global__ void __launch_bounds__(256)
k_xy(const void* __restrict__ A, const unsigned short* __restrict__ Bpk,
     const float* __restrict__ binf, const float* __restrict__ dis,
     unsigned short* __restrict__ Yb, const int* __restrict__ flags,
     int N, int Np) {
    __shared__ unsigned short Bs[6 * 2 * 4 * 64 * 8];  // 48 KB
    __shared__ unsigned short Xs[64 * 64];             // 8 KB (x, frag source)
    __shared__ unsigned short Ys[64 * 64];             // 8 KB (store staging)
    __shared__ float bs[64];
    int tid = threadIdx.x;
    for (int i = tid; i < 6 * 2 * 4 * 64; i += 256)
        ((uint4*)Bs)[i] = ((const uint4*)Bpk)[i];
    if (tid < 64) bs[tid] = binf[tid];
    __syncthreads();

    int w = tid >> 6, lane = tid & 63;
    int q = lane >> 4, n16 = lane & 15;
    int mrow = w * 16 + n16;                  // row this lane vector-stores
    int f = flags[0];
    int arow = min(blockIdx.x * 64 + mrow, N - 1);
    bf16x8 a0 = load_a8(A, f, (size_t)arow * 64 + 8 * q);
    bf16x8 a1 = load_a8(A, f, (size_t)arow * 64 + 8 * q + 32);

    float disv[4];
#pragma unroll
    for (int r = 0; r < 4; r++) {
        int node = blockIdx.x * 64 + w * 16 + 4 * q + r;
        disv[r] = dis[node];                  // dis has Np entries (padding 0)
    }

    size_t snode = (size_t)(blockIdx.x * 64 + mrow);  // store row node (< Np)

    // stage-1: x = A @ Win + b ; slot5 = x * dis (via LDS, vector stores)
#pragma unroll
    for (int nt = 0; nt < 4; nt++) {
        f32x4 d = {0.f, 0.f, 0.f, 0.f};
        bf16x8 b0 = *(const bf16x8*)(Bs + (size_t)(((0 * 2 + 0) * 4 + nt) * 64 + lane) * 8);
        bf16x8 b1 = *(const bf16x8*)(Bs + (size_t)(((0 * 2 + 1) * 4 + nt) * 64 + lane) * 8);
        d = __builtin_amdgcn_mfma_f32_16x16x32_bf16(a0, b0, d, 0, 0, 0);
        d = __builtin_amdgcn_mfma_f32_16x16x32_bf16(a1, b1, d, 0, 0, 0);
        int col = nt * 16 + n16;
#pragma unroll
        for (int r = 0; r < 4; r++) {
            int rowl = w * 16 + 4 * q + r;
            float xval = d[r] + bs[col];
            Xs[rowl * 64 + col] = f2bf(xval);
            Ys[rowl * 64 + col] = f2bf(xval * disv[r]);
        }
    }
    // same-wave LDS RAW (wave w wrote only rows w*16..w*16+15) -> no barrier
    {
        unsigned short* dst = Yb + ((size_t)5 * Np + snode) * 64;
        *(bf16x8*)(dst + 8 * q)      = *(const bf16x8*)(Ys + mrow * 64 + 8 * q);
        *(bf16x8*)(dst + 8 * q + 32) = *(const bf16x8*)(Ys + mrow * 64 + 8 * q + 32);
    }
    bf16x8 a20 = *(const bf16x8*)(Xs + mrow * 64 + 8 * q);
    bf16x8 a21 = *(const bf16x8*)(Xs + mrow * 64 + 8 * q + 32);

    for (int rel = 0; rel < REL; rel++) {
        int mat = 1 + rel;
#pragma unroll
        for (int nt = 0; nt < 4; nt++) {
            f32x4 d = {0.f, 0.f, 0.f, 0.f};
            bf16x8 b0 = *(const bf16x8*)(Bs + (size_t)(((mat * 2 + 0) * 4 + nt) * 64 + lane) * 8);
            bf16x8 b1 = *(const bf16x8*)(Bs + (size_t)(((mat * 2 + 1) * 4 + nt) * 64 + lane) * 8);
            d = __builtin_amdgcn_mfma_f32_16x16x32_bf16(a20, b0, d, 0, 0, 0);
            d = __builtin_amdgcn_mfma_f32_16x16x32_bf16(a21, b1, d, 0, 0, 0);
            int col = nt * 16 + n16;
#pragma unroll
            for (int r = 0; r < 4; r++)
                Ys[(w * 16 + 4 * q + r) * 64 + col] = f2bf(d[r]);
        }
        unsigned short* dst = Yb + ((size_t)rel * Np + snode) * 64;
        *(bf16x8*)(dst + 8 * q)      = *(const bf16x8*)(Ys + mrow * 64 + 8 * q);
        *(bf16x8*)(dst + 8 * q + 32) = *(const bf16x8*)(Ys + mrow * 64 + 8 * q + 32);
    }
}

// ---------------------------------------------------------------------------
// K_main: one node per wave; 2 half-waves split edges; lane = 2 channels.
// 2x edge unroll with independent accumulators (4 outstanding gathers).
// ---------------------------------------------------------------------------
__global__ void __launch_bounds__(256)
k_main(const unsigned short* __restrict__ Yb, const int* __restrict__ off,
       const unsigned* __restrict__ edata4, const float* __restrict__ dis,
       unsigned short* __restrict__ v, int N, int Np) {
    int tid = threadIdx.x;
    int wv = tid >> 6, lane = tid & 63;
    int n = blockIdx.x * 4 + wv;
    if (n >= N) return;
    int half = lane >> 5;
    int c2 = (lane & 31) * 2;
    int e0 = off[n], e1 = off[n + 1];
    float s0 = 0.f, s1 = 0.f, u0 = 0.f, u1 = 0.f, g0 = 0.f, g1 = 0.f;
    float s0b = 0.f, s1b = 0.f, u0b = 0.f, u1b = 0.f, g0b = 0.f, g1b = 0.f;
    const unsigned short* Yx = Yb + (size_t)5 * Np * 64;

    int e = e0 + half;
    for (; e + 2 < e1; e += 4) {
        unsigned mda = edata4[e];
        unsigned mdb = edata4[e + 2];
        int ca = mda & 0xFFFFF, ta = mda >> 20;
        int cb = mdb & 0xFFFFF, tb = mdb >> 20;
        unsigned yva = *(const unsigned*)(Yb + ((size_t)ta * Np + ca) * 64 + c2);
        unsigned xva = *(const unsigned*)(Yx + (size_t)ca * 64 + c2);
        unsigned yvb = *(const unsigned*)(Yb + ((size_t)tb * Np + cb) * 64 + c2);
        unsigned xvb = *(const unsigned*)(Yx + (size_t)cb * 64 + c2);
        float r0 = __uint_as_float(yva << 16);
        float r1 = __uint_as_float(yva & 0xFFFF0000u);
        g0 += __uint_as_float(xva << 16);
        g1 += __uint_as_float(xva & 0xFFFF0000u);
        float p0 = __expf(fminf(r0, 60.f));
        float p1 = __expf(fminf(r1, 60.f));
        s0 += p0; s1 += p1;
        u0 += r0 * p0; u1 += r1 * p1;
        float r0b = __uint_as_float(yvb << 16);
        float r1b = __uint_as_float(yvb & 0xFFFF0000u);
        g0b += __uint_as_float(xvb << 16);
        g1b += __uint_as_float(xvb & 0xFFFF0000u);
        float p0b = __expf(fminf(r0b, 60.f));
        float p1b = __expf(fminf(r1b, 60.f));
        s0b += p0b; s1b += p1b;
        u0b += r0b * p0b; u1b += r1b * p1b;
    }
    if (e < e1) {
        unsigned md = edata4[e];
        int c = md & 0xFFFFF, t = md >> 20;
        unsigned yv = *(const unsigned*)(Yb + ((size_t)t * Np + c) * 64 + c2);
        unsigned xv = *(const unsigned*)(Yx + (size_t)c * 64 + c2);
        float r0 = __uint_as_float(yv << 16);
        float r1 = __uint_as_float(yv & 0xFFFF0000u);
        g0 += __uint_as_float(xv << 16);
        g1 += __uint_as_float(xv & 0xFFFF0000u);
        float p0 = __expf(fminf(r0, 60.f));
        float p1 = __expf(fminf(r1, 60.f));
        s0 += p0; s1 += p1;
        u0 += r0 * p0; u1 += r1 * p1;
    }
    s0 += s0b; s1 += s1b; u0 += u0b; u1 += u1b; g0 += g0b; g1 += g1b;

    s0 += __shfl_xor(s0, 32); s1 += __shfl_xor(s1, 32);
    u0 += __shfl_xor(u0, 32); u1 += __shfl_xor(u1, 32);
    g0 += __shfl_xor(g0, 32); g1 += __shfl_xor(g1, 32);
    if (half == 0) {
        float dn = dis[n];
        float m0 = u0 / (s0 + 1e-16f), m1 = u1 / (s1 + 1e-16f);
        float v0 = g0 * dn + 0.5f * fmaxf(m0, 0.f);
        float v1 = g1 * dn + 0.5f * fmaxf(m1, 0.f);
        unsigned pack = (unsigned)f2bf(v0) | ((unsigned)f2bf(v1) << 16);
        *(unsigned*)(v + (size_t)n * 64 + c2) = pack;
    }
}

// ---------------------------------------------------------------------------
// K_out (MFMA): out = v @ Wout + bout. LDS-transposed vector stores.
// ---------------------------------------------------------------------------
__global__ void __launch_bounds__(256)
k_out(const unsigned short* __restrict__ v, const unsigned short* __restrict__ Bpk,
      const float* __restrict__ boutf, void* __restrict__ outv,
      const int* __restrict__ flags, int N, int Np) {
    __shared__ unsigned short Bs[2 * 4 * 64 * 8];  // 8 KB (mat 6)
    __shared__ float Os[64 * 64];                  // 16 KB staging
    __shared__ float bs[64];
    int tid = threadIdx.x;
    const unsigned short* src = Bpk + (size_t)6 * 2 * 4 * 64 * 8;
    for (int i = tid; i < 2 * 4 * 64; i += 256)
        ((uint4*)Bs)[i] = ((const uint4*)src)[i];
    if (tid < 64) bs[tid] = boutf[tid];
    __syncthreads();

    int w = tid >> 6, lane = tid & 63;
    int q = lane >> 4, n16 = lane & 15;
    int mrow = w * 16 + n16;
    int arow = min(blockIdx.x * 64 + mrow, N - 1);
    bf16x8 a0 = *(const bf16x8*)(v + (size_t)arow * 64 + 8 * q);
    bf16x8 a1 = *(const bf16x8*)(v + (size_t)arow * 64 + 8 * q + 32);
    int f = flags[0];
#pragma unroll
    for (int nt = 0; nt < 4; nt++) {
        f32x4 d = {0.f, 0.f, 0.f, 0.f};
        bf16x8 b0 = *(const bf16x8*)(Bs + (size_t)((0 * 4 + nt) * 64 + lane) * 8);
        bf16x8 b1 = *(const bf16x8*)(Bs + (size_t)((1 * 4 + nt) * 64 + lane) * 8);
        d = __builtin_amdgcn_mfma_f32_16x16x32_bf16(a0, b0, d, 0, 0, 0);
        d = __builtin_amdgcn_mfma_f32_16x16x32_bf16(a1, b1, d, 0, 0, 0);
        int col = nt * 16 + n16;
#pragma unroll
        for (int r = 0; r < 4; r++)
            Os[(w * 16 + 4 * q + r) * 64 + col] = d[r] + bs[col];
    }
    // same-wave rows -> no barrier. Vector-store row mrow.
    int node = blockIdx.x * 64 + mrow;
    if (node < N) {
        if (f) {
            float* dst = (float*)outv + (size_t)node * 64;
#pragma unroll
            for (int cchunk = 0; cchunk < 2; cchunk++) {
                int c0 = 8 * q + 32 * cchunk;
                *(f32x4*)(dst + c0)     = *(const f32x4*)(Os + mrow * 64 + c0);
                *(f32x4*)(dst + c0 + 4) = *(const f32x4*)(Os + mrow * 64 + c0 + 4);
            }
        } else {
            unsigned short* dst = (unsigned short*)outv + (size_t)node * 64;
#pragma unroll
            for (int cchunk = 0; cchunk < 2; cchunk++) {
                int c0 = 8 * q + 32 * cchunk;
                bf16x8 pk;
#pragma unroll
                for (int j = 0; j < 8; j++)
                    pk[j] = (short)f2bf(Os[mrow * 64 + c0 + j]);
                *(bf16x8*)(dst + c0) = pk;
            }
        }
    }
}

// ---------------------------------------------------------------------------
extern "C" void kernel_launch(void* const* d_in, const int* in_sizes, int n_in,
                              void* d_out, int out_size, void* d_ws, size_t ws_size,
                              hipStream_t stream) {
    const void* A    = d_in[0];
    const void* Win  = d_in[2];
    const void* bin  = d_in[3];
    const void* Wrel = d_in[4];
    const void* Wout = d_in[5];
    const void* bout = d_in[6];
    const int* ei = (const int*)d_in[7];
    const int* et = (const int*)d_in[8];
    int N = in_sizes[0] / HID;          // 50000
    int E = in_sizes[8];                // 800000
    int Np = ((N + 63) / 64) * 64;      // 50048
    int NB = Np / 64;                   // 782 buckets of 64 nodes
    int nblk = (E + EPB - 1) / EPB;     // 391 partition blocks
    int M = 2 * NB * nblk;              // concatenated hist length
    int nsb = (M + 1023) / 1024;        // scan blocks (<=1024 required)

    char* p = (char*)d_ws;
    auto carve = [&](size_t bytes) {
        char* q = p;
        p += (bytes + 15) & ~(size_t)15;
        return q;
    };
    unsigned short* Yb   = (unsigned short*)carve((size_t)6 * Np * 64 * 2);  // 38.4 MB
    unsigned short* vv   = (unsigned short*)carve((size_t)Np * 64 * 2);      // 6.4 MB
    unsigned*       rbuf = (unsigned*)carve((size_t)E * 4);                  // 3.2 MB
    unsigned char*  cb8  = (unsigned char*)carve((size_t)E);                 // 0.8 MB
    unsigned*       edata4 = (unsigned*)carve((size_t)E * 4);                // 3.2 MB
    int*            hist = (int*)carve((size_t)M * 4);                       // 2.45 MB
    unsigned short* Bpk  = (unsigned short*)carve((size_t)7 * 4096 * 2);
    float* binf  = (float*)carve(64 * 4);
    float* boutf = (float*)carve(64 * 4);
    int* off     = (int*)carve((size_t)(N + 1) * 4);
    float* dis   = (float*)carve((size_t)Np * 4);
    int* bsum    = (int*)carve((size_t)nsb * 4);
    int* flags   = (int*)carve(16);

    size_t lds_part = (size_t)2 * NB * 4;  // 6.3 KB dynamic LDS

    k_detect<<<1, 64, 0, stream>>>((const unsigned short*)bin, ei, flags);
    k_pack<<<14, 256, 0, stream>>>(Win, bin, Wrel, Wout, bout, Bpk, binf, boutf, flags);
    k_p1a<<<nblk, 256, lds_part, stream>>>(ei, flags, hist, E, NB, nblk);
    s_blk<<<nsb, 256, 0, stream>>>(hist, bsum, M);
    s_top<<<1, 256, 0, stream>>>(bsum, nsb);
    s_apply<<<nsb, 256, 0, stream>>>(hist, bsum, M);
    k_p1c<<<nblk, 256, lds_part, stream>>>(ei, et, flags, hist, rbuf, cb8, E, NB, nblk);
    k_p2r<<<NB, 256, 0, stream>>>(rbuf, hist, off, edata4, E, N, NB, nblk);
    k_p2c<<<NB, 256, 0, stream>>>(cb8, hist, dis, E, NB, nblk);
    k_xy<<<Np / 64, 256, 0, stream>>>(A, Bpk, binf, dis, Yb, flags, N, Np);
    k_main<<<(N + 3) / 4, 256, 0, stream>>>(Yb, off, edata4, dis, vv, N, Np);
    k_out<<<Np / 64, 256, 0, stream>>>(vv, Bpk, boutf, d_out, flags, N, Np);
}

// Round 9
// 201.171 us; speedup vs baseline: 3.4687x; 1.0709x over previous
//
#include <hip/hip_runtime.h>
#include <hip/hip_bf16.h>

#define HID 64
#define REL 5
#define EPB 4096          // edges per partition block (16/thread * 256)
#define BKT 256           // nodes per sort bucket

typedef short bf16x8 __attribute__((ext_vector_type(8)));
typedef float f32x4 __attribute__((ext_vector_type(4)));

__device__ __forceinline__ float bf2f(unsigned short u) {
    return __uint_as_float(((unsigned)u) << 16);
}
__device__ __forceinline__ unsigned short f2bf(float f) {
    __hip_bfloat16 h = (__hip_bfloat16)f;   // RNE
    return *(unsigned short*)&h;
}
__device__ __forceinline__ void dec_edge(const int* __restrict__ ei, int i64,
                                         int E, int e, int& r, int& c) {
    if (i64) { r = ei[2 * e]; c = ei[2 * (E + e)]; }
    else     { r = ei[e];     c = ei[E + e]; }
}

// ---------------------------------------------------------------------------
// K0: dtype detection. flags[0]=1 if f32, flags[1]=1 if int64 edge_index.
// ---------------------------------------------------------------------------
__global__ void k_detect(const unsigned short* __restrict__ wb,
                         const int* __restrict__ ei, int* flags) {
    int lane = threadIdx.x;  // 64 threads
    bool big = (lane < 32) ? (fabsf(bf2f(wb[2 * lane])) > 0.26f) : false;
    unsigned long long b1 = __ballot(big);
    bool odd_nz = (ei[2 * lane + 1] != 0);
    unsigned long long b2 = __ballot(odd_nz);
    if (lane == 0) {
        flags[0] = (b1 != 0ull) ? 1 : 0;
        flags[1] = (b2 == 0ull) ? 1 : 0;
    }
}

// ---------------------------------------------------------------------------
// K_pack: weights -> per-lane MFMA B-fragment order, bf16.
// Bpk[mat][ks][nt][lane][j]; mat: 0=Win, 1..5=Wrel, 6=Wout.
// ---------------------------------------------------------------------------
__global__ void k_pack(const void* Win, const void* bin, const void* Wr,
                       const void* Wout, const void* bout,
                       unsigned short* __restrict__ Bpk,
                       float* __restrict__ binf, float* __restrict__ boutf,
                       const int* __restrict__ flags) {
    int f = flags[0];
    int gid = blockIdx.x * 256 + threadIdx.x;
    if (gid < 7 * 2 * 4 * 64) {
        int lane = gid & 63;
        int nt = (gid >> 6) & 3;
        int ks = (gid >> 8) & 1;
        int mat = gid >> 9;
        int q = lane >> 4, n = nt * 16 + (lane & 15);
#pragma unroll
        for (int j = 0; j < 8; j++) {
            int k = ks * 32 + q * 8 + j;
            int idx = k * 64 + n;
            float val;
            if (mat == 0)
                val = f ? ((const float*)Win)[idx] : bf2f(((const unsigned short*)Win)[idx]);
            else if (mat <= 5) {
                int ii = (mat - 1) * 4096 + idx;
                val = f ? ((const float*)Wr)[ii] : bf2f(((const unsigned short*)Wr)[ii]);
            } else
                val = f ? ((const float*)Wout)[idx] : bf2f(((const unsigned short*)Wout)[idx]);
            Bpk[(size_t)gid * 8 + j] = f2bf(val);
        }
    }
    if (gid < 64)
        binf[gid] = f ? ((const float*)bin)[gid] : bf2f(((const unsigned short*)bin)[gid]);
    else if (gid >= 64 && gid < 128) {
        int i = gid - 64;
        boutf[i] = f ? ((const float*)bout)[i] : bf2f(((const unsigned short*)bout)[i]);
    }
}

// ---------------------------------------------------------------------------
// P1a: per-block LDS histograms of r/BKT and c/BKT.
// hist layout: [bin*nblk + blk] for R, then +NB*nblk for C.
// ---------------------------------------------------------------------------
__global__ void k_p1a(const int* __restrict__ ei, const int* __restrict__ flags,
                      int* __restrict__ hist, int E, int NB, int nblk) {
    extern __shared__ int lh[];  // 2*NB
    int tid = threadIdx.x, blk = blockIdx.x;
    for (int i = tid; i < 2 * NB; i += 256) lh[i] = 0;
    __syncthreads();
    int i64 = flags[1];
#pragma unroll
    for (int k = 0; k < EPB / 256; k++) {
        int e = blk * EPB + k * 256 + tid;
        if (e < E) {
            int r, c;
            dec_edge(ei, i64, E, e, r, c);
            atomicAdd(&lh[r >> 8], 1);
            atomicAdd(&lh[NB + (c >> 8)], 1);
        }
    }
    __syncthreads();
    int NBn = NB * nblk;
    for (int i = tid; i < NB; i += 256) {
        hist[i * nblk + blk] = lh[i];
        hist[NBn + i * nblk + blk] = lh[NB + i];
    }
}

// ---------------------------------------------------------------------------
// Generic exclusive scan over M ints (in-place), 3 kernels, CHUNK=1024.
// ---------------------------------------------------------------------------
__global__ void s_blk(const int* __restrict__ v, int* __restrict__ bsum, int M) {
    __shared__ int red[256];
    int t = threadIdx.x;
    int i0 = blockIdx.x * 1024 + t * 4;
    int s = 0;
#pragma unroll
    for (int j = 0; j < 4; j++) { int i = i0 + j; if (i < M) s += v[i]; }
    red[t] = s;
    __syncthreads();
    for (int d = 128; d > 0; d >>= 1) {
        if (t < d) red[t] += red[t + d];
        __syncthreads();
    }
    if (t == 0) bsum[blockIdx.x] = red[0];
}

__global__ void s_top(int* __restrict__ bsum, int nsb) {
    __shared__ int v[1024];
    int t = threadIdx.x;
    for (int i = t; i < nsb; i += 256) v[i] = bsum[i];
    __syncthreads();
    if (t == 0) {
        int run = 0;
        for (int i = 0; i < nsb; i++) { int x = v[i]; v[i] = run; run += x; }
    }
    __syncthreads();
    for (int i = t; i < nsb; i += 256) bsum[i] = v[i];
}

__global__ void s_apply(int* __restrict__ v, const int* __restrict__ bsum, int M) {
    __shared__ int red[256];
    int t = threadIdx.x;
    int i0 = blockIdx.x * 1024 + t * 4;
    int x[4];
    int s = 0;
#pragma unroll
    for (int j = 0; j < 4; j++) {
        int i = i0 + j;
        x[j] = (i < M) ? v[i] : 0;
        s += x[j];
    }
    red[t] = s;
    __syncthreads();
    for (int d = 1; d < 256; d <<= 1) {
        int add = (t >= d) ? red[t - d] : 0;
        __syncthreads();
        red[t] += add;
        __syncthreads();
    }
    int run = bsum[blockIdx.x] + red[t] - s;
#pragma unroll
    for (int j = 0; j < 4; j++) {
        int i = i0 + j;
        if (i < M) { int tmp = x[j]; v[i] = run; run += tmp; }
    }
}

// ---------------------------------------------------------------------------
// P1c: partition. rbuf[posR] = (r&255)<<20 | t<<17 | c ; cb8[posC] = c&255.
// ---------------------------------------------------------------------------
__global__ void k_p1c(const int* __restrict__ ei, const int* __restrict__ et,
                      const int* __restrict__ flags, const int* __restrict__ hist,
                      unsigned* __restrict__ rbuf, unsigned char* __restrict__ cb8,
                      int E, int NB, int nblk) {
    extern __shared__ int lh[];  // 2*NB rank counters
    int tid = threadIdx.x, blk = blockIdx.x;
    for (int i = tid; i < 2 * NB; i += 256) lh[i] = 0;
    __syncthreads();
    int i64 = flags[1];
    int NBn = NB * nblk;
#pragma unroll
    for (int k = 0; k < EPB / 256; k++) {
        int e = blk * EPB + k * 256 + tid;
        if (e < E) {
            int r, c;
            dec_edge(ei, i64, E, e, r, c);
            int t = et[e];
            int binR = r >> 8;
            int posR = hist[binR * nblk + blk] + atomicAdd(&lh[binR], 1);
            rbuf[posR] = ((unsigned)(r & 255) << 20) | ((unsigned)t << 17) | (unsigned)c;
            int binC = c >> 8;
            int posC = hist[NBn + binC * nblk + blk] - E + atomicAdd(&lh[NB + binC], 1);
            cb8[posC] = (unsigned char)(c & 255);
        }
    }
}

// ---------------------------------------------------------------------------
// P2 (merged): blocks [0,NB) = r-side (off[] + final edata4);
//              blocks [NB,2NB) = c-side (dis[]). BKT=256 nodes per bucket.
// ---------------------------------------------------------------------------
__global__ void k_p2(const unsigned* __restrict__ rbuf, const unsigned char* __restrict__ cb8,
                     const int* __restrict__ hist,
                     int* __restrict__ off, unsigned* __restrict__ edata4,
                     float* __restrict__ dis, int E, int N, int NB, int nblk) {
    __shared__ int lcnt[BKT], excl[BKT], lcnt2[BKT];
    int tid = threadIdx.x;
    int bk = blockIdx.x;
    if (bk < NB) {
        // ---- r-side ----
        int bstart = hist[bk * nblk];
        int bend = (bk + 1 < NB) ? hist[(bk + 1) * nblk] : E;
        lcnt[tid] = 0; lcnt2[tid] = 0;
        __syncthreads();
        for (int e = bstart + tid; e < bend; e += 256)
            atomicAdd(&lcnt[(rbuf[e] >> 20) & 255], 1);
        __syncthreads();
        // parallel exclusive scan over 256 bins (Hillis-Steele)
        int s = lcnt[tid];
        excl[tid] = s;
        __syncthreads();
        for (int d = 1; d < 256; d <<= 1) {
            int add = (tid >= d) ? excl[tid - d] : 0;
            __syncthreads();
            excl[tid] += add;
            __syncthreads();
        }
        int base = excl[tid] - s;   // exclusive
        excl[tid] = base;
        __syncthreads();
        int node = bk * BKT + tid;
        if (node < N) off[node] = bstart + base;
        if (bk == 0 && tid == 0) off[N] = E;
        for (int e = bstart + tid; e < bend; e += 256) {
            unsigned rec = rbuf[e];
            int rl = (rec >> 20) & 255;
            int t = (rec >> 17) & 7;
            int c = rec & 0x1FFFF;
            int pos = bstart + excl[rl] + atomicAdd(&lcnt2[rl], 1);
            edata4[pos] = (unsigned)c | ((unsigned)t << 20);
        }
    } else {
        // ---- c-side ----
        int bk2 = bk - NB;
        int NBn = NB * nblk;
        int cstart = hist[NBn + bk2 * nblk] - E;
        int cend = (bk2 + 1 < NB) ? hist[NBn + (bk2 + 1) * nblk] - E : E;
        lcnt[tid] = 0;
        __syncthreads();
        for (int e = cstart + tid; e < cend; e += 256)
            atomicAdd(&lcnt[cb8[e]], 1);
        __syncthreads();
        int node = bk2 * BKT + tid;   // covers all Np
        int d = lcnt[tid];
        dis[node] = (d > 0) ? rsqrtf((float)d) : 0.f;   // padding nodes -> 0
    }
}

// ---------------------------------------------------------------------------
// K_xy (MFMA): x = A@Win + b ; Y[r] = bf16(x)@Wrel[r].
// Yi layout [5][Np] rows of 128 ushorts: pos 2*ch = y[ch], 2*ch+1 = (x*dis)[ch].
// ---------------------------------------------------------------------------
__device__ __forceinline__ bf16x8 load_a8(const void* A, int f, size_t base) {
    if (f) {
        const float* Af = (const float*)A + base;
        bf16x8 r;
#pragma unroll
        for (int j = 0; j < 8; j++) r[j] = (short)f2bf(Af[j]);
        return r;
    }
    return *(const bf16x8*)((const unsigned short*)A + base);
}

__global__ void __launch_bounds__(256)
k_xy(const void* __restrict__ A, const unsigned short* __restrict__ Bpk,
     const float* __restrict__ binf, const float* __restrict__ dis,
     unsigned short* __restrict__ Yi, const int* __restrict__ flags,
     int N, int Np) {
    __shared__ unsigned short Bs[6 * 2 * 4 * 64 * 8];  // 48 KB
    __shared__ unsigned short Xs[64 * 64];             // 8 KB  x (frag source)
    __shared__ unsigned short Xss[64 * 64];            // 8 KB  x*dis
    __shared__ unsigned short Ys[64 * 64];             // 8 KB  y staging
    __shared__ float bs[64];
    int tid = threadIdx.x;
    for (int i = tid; i < 6 * 2 * 4 * 64; i += 256)
        ((uint4*)Bs)[i] = ((const uint4*)Bpk)[i];
    if (tid < 64) bs[tid] = binf[tid];
    __syncthreads();

    int w = tid >> 6, lane = tid & 63;
    int q = lane >> 4, n16 = lane & 15;
    int mrow = w * 16 + n16;                  // row this lane vector-stores
    int f = flags[0];
    int arow = min(blockIdx.x * 64 + mrow, N - 1);
    bf16x8 a0 = load_a8(A, f, (size_t)arow * 64 + 8 * q);
    bf16x8 a1 = load_a8(A, f, (size_t)arow * 64 + 8 * q + 32);

    float disv[4];
#pragma unroll
    for (int r = 0; r < 4; r++) {
        int node = blockIdx.x * 64 + w * 16 + 4 * q + r;
        disv[r] = dis[node];                  // dis has Np entries (padding 0)
    }

    size_t snode = (size_t)(blockIdx.x * 64 + mrow);

    // stage-1: x = A @ Win + b ; Xs = x, Xss = x*dis
#pragma unroll
    for (int nt = 0; nt < 4; nt++) {
        f32x4 d = {0.f, 0.f, 0.f, 0.f};
        bf16x8 b0 = *(const bf16x8*)(Bs + (size_t)(((0 * 2 + 0) * 4 + nt) * 64 + lane) * 8);
        bf16x8 b1 = *(const bf16x8*)(Bs + (size_t)(((0 * 2 + 1) * 4 + nt) * 64 + lane) * 8);
        d = __builtin_amdgcn_mfma_f32_16x16x32_bf16(a0, b0, d, 0, 0, 0);
        d = __builtin_amdgcn_mfma_f32_16x16x32_bf16(a1, b1, d, 0, 0, 0);
        int col = nt * 16 + n16;
#pragma unroll
        for (int r = 0; r < 4; r++) {
            int rowl = w * 16 + 4 * q + r;
            float xval = d[r] + bs[col];
            Xs[rowl * 64 + col] = f2bf(xval);
            Xss[rowl * 64 + col] = f2bf(xval * disv[r]);
        }
    }
    // same-wave LDS RAW (wave w wrote only rows w*16..w*16+15) -> no barrier
    bf16x8 a20 = *(const bf16x8*)(Xs + mrow * 64 + 8 * q);
    bf16x8 a21 = *(const bf16x8*)(Xs + mrow * 64 + 8 * q + 32);

    for (int rel = 0; rel < REL; rel++) {
        int mat = 1 + rel;
#pragma unroll
        for (int nt = 0; nt < 4; nt++) {
            f32x4 d = {0.f, 0.f, 0.f, 0.f};
            bf16x8 b0 = *(const bf16x8*)(Bs + (size_t)(((mat * 2 + 0) * 4 + nt) * 64 + lane) * 8);
            bf16x8 b1 = *(const bf16x8*)(Bs + (size_t)(((mat * 2 + 1) * 4 + nt) * 64 + lane) * 8);
            d = __builtin_amdgcn_mfma_f32_16x16x32_bf16(a20, b0, d, 0, 0, 0);
            d = __builtin_amdgcn_mfma_f32_16x16x32_bf16(a21, b1, d, 0, 0, 0);
            int col = nt * 16 + n16;
#pragma unroll
            for (int r = 0; r < 4; r++)
                Ys[(w * 16 + 4 * q + r) * 64 + col] = f2bf(d[r]);
        }
        // interleave {y, x*dis} and store row mrow (4 lanes q=0..3 cover it)
        unsigned short* dst = Yi + ((size_t)rel * Np + snode) * 128;
#pragma unroll
        for (int ch = 0; ch < 2; ch++) {
            int c0 = 8 * q + 32 * ch;
            bf16x8 y8 = *(const bf16x8*)(Ys + mrow * 64 + c0);
            bf16x8 x8 = *(const bf16x8*)(Xss + mrow * 64 + c0);
            bf16x8 lo, hi;
#pragma unroll
            for (int j = 0; j < 4; j++) {
                lo[2 * j] = y8[j];     lo[2 * j + 1] = x8[j];
                hi[2 * j] = y8[4 + j]; hi[2 * j + 1] = x8[4 + j];
            }
            *(bf16x8*)(dst + 2 * c0)     = lo;
            *(bf16x8*)(dst + 2 * c0 + 8) = hi;
        }
    }
}

// ---------------------------------------------------------------------------
// K_main: one node per wave; 2 half-waves split edges; lane = 2 channels.
// One uint2 (8B) load per edge per lane: interleaved {y,xs} row.
// ---------------------------------------------------------------------------
__global__ void __launch_bounds__(256)
k_main(const unsigned short* __restrict__ Yi, const int* __restrict__ off,
       const unsigned* __restrict__ edata4, const float* __restrict__ dis,
       unsigned short* __restrict__ v, int N, int Np) {
    int tid = threadIdx.x;
    int wv = tid >> 6, lane = tid & 63;
    int n = blockIdx.x * 4 + wv;
    if (n >= N) return;
    int half = lane >> 5;
    int co = (lane & 31) * 4;                 // ushort offset within 128-row
    int e0 = off[n], e1 = off[n + 1];
    float s0 = 0.f, s1 = 0.f, u0 = 0.f, u1 = 0.f, g0 = 0.f, g1 = 0.f;
    float s0b = 0.f, s1b = 0.f, u0b = 0.f, u1b = 0.f, g0b = 0.f, g1b = 0.f;

    int e = e0 + half;
    for (; e + 2 < e1; e += 4) {
        unsigned mda = edata4[e];
        unsigned mdb = edata4[e + 2];
        int ca = mda & 0xFFFFF, ta = mda >> 20;
        int cb = mdb & 0xFFFFF, tb = mdb >> 20;
        uint2 ya = *(const uint2*)(Yi + ((size_t)ta * Np + ca) * 128 + co);
        uint2 yb = *(const uint2*)(Yi + ((size_t)tb * Np + cb) * 128 + co);
        float r0 = __uint_as_float(ya.x << 16);
        float r1 = __uint_as_float(ya.y << 16);
        g0 += __uint_as_float(ya.x & 0xFFFF0000u);
        g1 += __uint_as_float(ya.y & 0xFFFF0000u);
        float p0 = __expf(fminf(r0, 60.f));
        float p1 = __expf(fminf(r1, 60.f));
        s0 += p0; s1 += p1;
        u0 += r0 * p0; u1 += r1 * p1;
        float r0b = __uint_as_float(yb.x << 16);
        float r1b = __uint_as_float(yb.y << 16);
        g0b += __uint_as_float(yb.x & 0xFFFF0000u);
        g1b += __uint_as_float(yb.y & 0xFFFF0000u);
        float p0b = __expf(fminf(r0b, 60.f));
        float p1b = __expf(fminf(r1b, 60.f));
        s0b += p0b; s1b += p1b;
        u0b += r0b * p0b; u1b += r1b * p1b;
    }
    if (e < e1) {
        unsigned md = edata4[e];
        int c = md & 0xFFFFF, t = md >> 20;
        uint2 ya = *(const uint2*)(Yi + ((size_t)t * Np + c) * 128 + co);
        float r0 = __uint_as_float(ya.x << 16);
        float r1 = __uint_as_float(ya.y << 16);
        g0 += __uint_as_float(ya.x & 0xFFFF0000u);
        g1 += __uint_as_float(ya.y & 0xFFFF0000u);
        float p0 = __expf(fminf(r0, 60.f));
        float p1 = __expf(fminf(r1, 60.f));
        s0 += p0; s1 += p1;
        u0 += r0 * p0; u1 += r1 * p1;
    }
    s0 += s0b; s1 += s1b; u0 += u0b; u1 += u1b; g0 += g0b; g1 += g1b;

    s0 += __shfl_xor(s0, 32); s1 += __shfl_xor(s1, 32);
    u0 += __shfl_xor(u0, 32); u1 += __shfl_xor(u1, 32);
    g0 += __shfl_xor(g0, 32); g1 += __shfl_xor(g1, 32);
    if (half == 0) {
        float dn = dis[n];
        float m0 = u0 / (s0 + 1e-16f), m1 = u1 / (s1 + 1e-16f);
        float v0 = g0 * dn + 0.5f * fmaxf(m0, 0.f);
        float v1 = g1 * dn + 0.5f * fmaxf(m1, 0.f);
        unsigned pack = (unsigned)f2bf(v0) | ((unsigned)f2bf(v1) << 16);
        *(unsigned*)(v + (size_t)n * 64 + (lane & 31) * 2) = pack;
    }
}

// ---------------------------------------------------------------------------
// K_out (MFMA): out = v @ Wout + bout. LDS-transposed vector stores.
// ---------------------------------------------------------------------------
__global__ void __launch_bounds__(256)
k_out(const unsigned short* __restrict__ v, const unsigned short* __restrict__ Bpk,
      const float* __restrict__ boutf, void* __restrict__ outv,
      const int* __restrict__ flags, int N, int Np) {
    __shared__ unsigned short Bs[2 * 4 * 64 * 8];  // 8 KB (mat 6)
    __shared__ float Os[64 * 64];                  // 16 KB staging
    __shared__ float bs[64];
    int tid = threadIdx.x;
    const unsigned short* src = Bpk + (size_t)6 * 2 * 4 * 64 * 8;
    for (int i = tid; i < 2 * 4 * 64; i += 256)
        ((uint4*)Bs)[i] = ((const uint4*)src)[i];
    if (tid < 64) bs[tid] = boutf[tid];
    __syncthreads();

    int w = tid >> 6, lane = tid & 63;
    int q = lane >> 4, n16 = lane & 15;
    int mrow = w * 16 + n16;
    int arow = min(blockIdx.x * 64 + mrow, N - 1);
    bf16x8 a0 = *(const bf16x8*)(v + (size_t)arow * 64 + 8 * q);
    bf16x8 a1 = *(const bf16x8*)(v + (size_t)arow * 64 + 8 * q + 32);
    int f = flags[0];
#pragma unroll
    for (int nt = 0; nt < 4; nt++) {
        f32x4 d = {0.f, 0.f, 0.f, 0.f};
        bf16x8 b0 = *(const bf16x8*)(Bs + (size_t)((0 * 4 + nt) * 64 + lane) * 8);
        bf16x8 b1 = *(const bf16x8*)(Bs + (size_t)((1 * 4 + nt) * 64 + lane) * 8);
        d = __builtin_amdgcn_mfma_f32_16x16x32_bf16(a0, b0, d, 0, 0, 0);
        d = __builtin_amdgcn_mfma_f32_16x16x32_bf16(a1, b1, d, 0, 0, 0);
        int col = nt * 16 + n16;
#pragma unroll
        for (int r = 0; r < 4; r++)
            Os[(w * 16 + 4 * q + r) * 64 + col] = d[r] + bs[col];
    }
    // same-wave rows -> no barrier. Vector-store row mrow.
    int node = blockIdx.x * 64 + mrow;
    if (node < N) {
        if (f) {
            float* dst = (float*)outv + (size_t)node * 64;
#pragma unroll
            for (int cchunk = 0; cchunk < 2; cchunk++) {
                int c0 = 8 * q + 32 * cchunk;
                *(f32x4*)(dst + c0)     = *(const f32x4*)(Os + mrow * 64 + c0);
                *(f32x4*)(dst + c0 + 4) = *(const f32x4*)(Os + mrow * 64 + c0 + 4);
            }
        } else {
            unsigned short* dst = (unsigned short*)outv + (size_t)node * 64;
#pragma unroll
            for (int cchunk = 0; cchunk < 2; cchunk++) {
                int c0 = 8 * q + 32 * cchunk;
                bf16x8 pk;
#pragma unroll
                for (int j = 0; j < 8; j++)
                    pk[j] = (short)f2bf(Os[mrow * 64 + c0 + j]);
                *(bf16x8*)(dst + c0) = pk;
            }
        }
    }
}

// ---------------------------------------------------------------------------
extern "C" void kernel_launch(void* const* d_in, const int* in_sizes, int n_in,
                              void* d_out, int out_size, void* d_ws, size_t ws_size,
                              hipStream_t stream) {
    const void* A    = d_in[0];
    const void* Win  = d_in[2];
    const void* bin  = d_in[3];
    const void* Wrel = d_in[4];
    const void* Wout = d_in[5];
    const void* bout = d_in[6];
    const int* ei = (const int*)d_in[7];
    const int* et = (const int*)d_in[8];
    int N = in_sizes[0] / HID;          // 50000
    int E = in_sizes[8];                // 800000
    int Np = ((N + BKT - 1) / BKT) * BKT;  // 50176 (multiple of 256 and 64)
    int NB = Np / BKT;                  // 196 buckets of 256 nodes
    int nblk = (E + EPB - 1) / EPB;     // 196 partition blocks
    int M = 2 * NB * nblk;              // concatenated hist length (~77K)
    int nsb = (M + 1023) / 1024;        // scan blocks (<=1024 required)

    char* p = (char*)d_ws;
    auto carve = [&](size_t bytes) {
        char* q = p;
        p += (bytes + 15) & ~(size_t)15;
        return q;
    };
    unsigned short* Yi   = (unsigned short*)carve((size_t)REL * Np * 128 * 2); // 64.2 MB
    unsigned short* vv   = (unsigned short*)carve((size_t)Np * 64 * 2);        // 6.4 MB
    unsigned*       rbuf = (unsigned*)carve((size_t)E * 4);                    // 3.2 MB
    unsigned char*  cb8  = (unsigned char*)carve((size_t)E);                   // 0.8 MB
    unsigned*       edata4 = (unsigned*)carve((size_t)E * 4);                  // 3.2 MB
    int*            hist = (int*)carve((size_t)M * 4);                         // 0.3 MB
    unsigned short* Bpk  = (unsigned short*)carve((size_t)7 * 4096 * 2);
    float* binf  = (float*)carve(64 * 4);
    float* boutf = (float*)carve(64 * 4);
    int* off     = (int*)carve((size_t)(N + 1) * 4);
    float* dis   = (float*)carve((size_t)Np * 4);
    int* bsum    = (int*)carve((size_t)nsb * 4);
    int* flags   = (int*)carve(16);

    size_t lds_part = (size_t)2 * NB * 4;  // 1.6 KB dynamic LDS

    k_detect<<<1, 64, 0, stream>>>((const unsigned short*)bin, ei, flags);
    k_pack<<<14, 256, 0, stream>>>(Win, bin, Wrel, Wout, bout, Bpk, binf, boutf, flags);
    k_p1a<<<nblk, 256, lds_part, stream>>>(ei, flags, hist, E, NB, nblk);
    s_blk<<<nsb, 256, 0, stream>>>(hist, bsum, M);
    s_top<<<1, 256, 0, stream>>>(bsum, nsb);
    s_apply<<<nsb, 256, 0, stream>>>(hist, bsum, M);
    k_p1c<<<nblk, 256, lds_part, stream>>>(ei, et, flags, hist, rbuf, cb8, E, NB, nblk);
    k_p2<<<2 * NB, 256, 0, stream>>>(rbuf, cb8, hist, off, edata4, dis, E, N, NB, nblk);
    k_xy<<<Np / 64, 256, 0, stream>>>(A, Bpk, binf, dis, Yi, flags, N, Np);
    k_main<<<(N + 3) / 4, 256, 0, stream>>>(Yi, off, edata4, dis, vv, N, Np);
    k_out<<<Np / 64, 256, 0, stream>>>(vv, Bpk, boutf, d_out, flags, N, Np);
}

// Round 10
// 194.931 us; speedup vs baseline: 3.5797x; 1.0320x over previous
//
#include <hip/hip_runtime.h>
#include <hip/hip_bf16.h>

#define HID 64
#define REL 5
#define EPB 4096          // edges per partition block (16/thread * 256)
#define BKT 256           // nodes per sort bucket

typedef short bf16x8 __attribute__((ext_vector_type(8)));
typedef float f32x4 __attribute__((ext_vector_type(4)));

__device__ __forceinline__ float bf2f(unsigned short u) {
    return __uint_as_float(((unsigned)u) << 16);
}
__device__ __forceinline__ unsigned short f2bf(float f) {
    __hip_bfloat16 h = (__hip_bfloat16)f;   // RNE
    return *(unsigned short*)&h;
}
// Per-wave inline dtype detection (no separate kernel, no flags buffer).
// f32 if any probed bf16-view entry of W_in_b (~U(-1/8,1/8)) is "big".
__device__ __forceinline__ int det_f32(const unsigned short* __restrict__ wb) {
    int lane = threadIdx.x & 63;
    bool big = (lane < 32) ? (fabsf(bf2f(wb[2 * lane])) > 0.26f) : false;
    return (__ballot(big) != 0ull) ? 1 : 0;
}
// int64 edge_index iff all odd int32 words are zero.
__device__ __forceinline__ int det_i64(const int* __restrict__ ei) {
    int lane = threadIdx.x & 63;
    bool odd_nz = (ei[2 * lane + 1] != 0);
    return (__ballot(odd_nz) == 0ull) ? 1 : 0;
}
__device__ __forceinline__ void dec_edge(const int* __restrict__ ei, int i64,
                                         int E, int e, int& r, int& c) {
    if (i64) { r = ei[2 * e]; c = ei[2 * (E + e)]; }
    else     { r = ei[e];     c = ei[E + e]; }
}

// ---------------------------------------------------------------------------
// K_pack: weights -> per-lane MFMA B-fragment order, bf16.
// Bpk[mat][ks][nt][lane][j]; mat: 0=Win, 1..5=Wrel, 6=Wout.
// ---------------------------------------------------------------------------
__global__ void k_pack(const void* Win, const void* bin, const void* Wr,
                       const void* Wout, const void* bout,
                       unsigned short* __restrict__ Bpk,
                       float* __restrict__ binf, float* __restrict__ boutf) {
    int f = det_f32((const unsigned short*)bin);
    int gid = blockIdx.x * 256 + threadIdx.x;
    if (gid < 7 * 2 * 4 * 64) {
        int lane = gid & 63;
        int nt = (gid >> 6) & 3;
        int ks = (gid >> 8) & 1;
        int mat = gid >> 9;
        int q = lane >> 4, n = nt * 16 + (lane & 15);
#pragma unroll
        for (int j = 0; j < 8; j++) {
            int k = ks * 32 + q * 8 + j;
            int idx = k * 64 + n;
            float val;
            if (mat == 0)
                val = f ? ((const float*)Win)[idx] : bf2f(((const unsigned short*)Win)[idx]);
            else if (mat <= 5) {
                int ii = (mat - 1) * 4096 + idx;
                val = f ? ((const float*)Wr)[ii] : bf2f(((const unsigned short*)Wr)[ii]);
            } else
                val = f ? ((const float*)Wout)[idx] : bf2f(((const unsigned short*)Wout)[idx]);
            Bpk[(size_t)gid * 8 + j] = f2bf(val);
        }
    }
    if (gid < 64)
        binf[gid] = f ? ((const float*)bin)[gid] : bf2f(((const unsigned short*)bin)[gid]);
    else if (gid >= 64 && gid < 128) {
        int i = gid - 64;
        boutf[i] = f ? ((const float*)bout)[i] : bf2f(((const unsigned short*)bout)[i]);
    }
}

// ---------------------------------------------------------------------------
// P1a: per-block LDS histograms of r/BKT and c/BKT.
// hist layout: [bin*nblk + blk] for R, then +NB*nblk for C.
// ---------------------------------------------------------------------------
__global__ void k_p1a(const int* __restrict__ ei,
                      int* __restrict__ hist, int E, int NB, int nblk) {
    extern __shared__ int lh[];  // 2*NB
    int i64 = det_i64(ei);
    int tid = threadIdx.x, blk = blockIdx.x;
    for (int i = tid; i < 2 * NB; i += 256) lh[i] = 0;
    __syncthreads();
#pragma unroll
    for (int k = 0; k < EPB / 256; k++) {
        int e = blk * EPB + k * 256 + tid;
        if (e < E) {
            int r, c;
            dec_edge(ei, i64, E, e, r, c);
            atomicAdd(&lh[r >> 8], 1);
            atomicAdd(&lh[NB + (c >> 8)], 1);
        }
    }
    __syncthreads();
    int NBn = NB * nblk;
    for (int i = tid; i < NB; i += 256) {
        hist[i * nblk + blk] = lh[i];
        hist[NBn + i * nblk + blk] = lh[NB + i];
    }
}

// ---------------------------------------------------------------------------
// Scan (2 kernels): s_blk computes per-1024-chunk sums; s_apply re-derives the
// chunk base by reducing bsum[i<bk] (nsb is small) then applies in-place.
// ---------------------------------------------------------------------------
__global__ void s_blk(const int* __restrict__ v, int* __restrict__ bsum, int M) {
    __shared__ int red[256];
    int t = threadIdx.x;
    int i0 = blockIdx.x * 1024 + t * 4;
    int s = 0;
#pragma unroll
    for (int j = 0; j < 4; j++) { int i = i0 + j; if (i < M) s += v[i]; }
    red[t] = s;
    __syncthreads();
    for (int d = 128; d > 0; d >>= 1) {
        if (t < d) red[t] += red[t + d];
        __syncthreads();
    }
    if (t == 0) bsum[blockIdx.x] = red[0];
}

__global__ void s_apply(int* __restrict__ v, const int* __restrict__ bsum,
                        int M, int nsb) {
    __shared__ int red[256];
    int t = threadIdx.x, bk = blockIdx.x;
    // base = sum of bsum[i] for i < bk
    int acc = 0;
    for (int i = t; i < nsb; i += 256)
        if (i < bk) acc += bsum[i];
    red[t] = acc;
    __syncthreads();
    for (int d = 128; d > 0; d >>= 1) {
        if (t < d) red[t] += red[t + d];
        __syncthreads();
    }
    int base = red[0];
    __syncthreads();
    // local exclusive scan of this chunk
    int i0 = bk * 1024 + t * 4;
    int x[4];
    int s = 0;
#pragma unroll
    for (int j = 0; j < 4; j++) {
        int i = i0 + j;
        x[j] = (i < M) ? v[i] : 0;
        s += x[j];
    }
    red[t] = s;
    __syncthreads();
    for (int d = 1; d < 256; d <<= 1) {
        int add = (t >= d) ? red[t - d] : 0;
        __syncthreads();
        red[t] += add;
        __syncthreads();
    }
    int run = base + red[t] - s;
#pragma unroll
    for (int j = 0; j < 4; j++) {
        int i = i0 + j;
        if (i < M) { int tmp = x[j]; v[i] = run; run += tmp; }
    }
}

// ---------------------------------------------------------------------------
// P1c: partition. rbuf[posR] = (r&255)<<20 | t<<17 | c ; cb8[posC] = c&255.
// ---------------------------------------------------------------------------
__global__ void k_p1c(const int* __restrict__ ei, const int* __restrict__ et,
                      const int* __restrict__ hist,
                      unsigned* __restrict__ rbuf, unsigned char* __restrict__ cb8,
                      int E, int NB, int nblk) {
    extern __shared__ int lh[];  // 2*NB rank counters
    int i64 = det_i64(ei);
    int tid = threadIdx.x, blk = blockIdx.x;
    for (int i = tid; i < 2 * NB; i += 256) lh[i] = 0;
    __syncthreads();
    int NBn = NB * nblk;
#pragma unroll
    for (int k = 0; k < EPB / 256; k++) {
        int e = blk * EPB + k * 256 + tid;
        if (e < E) {
            int r, c;
            dec_edge(ei, i64, E, e, r, c);
            int t = et[e];
            int binR = r >> 8;
            int posR = hist[binR * nblk + blk] + atomicAdd(&lh[binR], 1);
            rbuf[posR] = ((unsigned)(r & 255) << 20) | ((unsigned)t << 17) | (unsigned)c;
            int binC = c >> 8;
            int posC = hist[NBn + binC * nblk + blk] - E + atomicAdd(&lh[NB + binC], 1);
            cb8[posC] = (unsigned char)(c & 255);
        }
    }
}

// ---------------------------------------------------------------------------
// P2 (merged): blocks [0,NB) = r-side (off[] + final edata4);
//              blocks [NB,2NB) = c-side (dis[]). BKT=256 nodes per bucket.
// ---------------------------------------------------------------------------
__global__ void k_p2(const unsigned* __restrict__ rbuf, const unsigned char* __restrict__ cb8,
                     const int* __restrict__ hist,
                     int* __restrict__ off, unsigned* __restrict__ edata4,
                     float* __restrict__ dis, int E, int N, int NB, int nblk) {
    __shared__ int lcnt[BKT], excl[BKT], lcnt2[BKT];
    int tid = threadIdx.x;
    int bk = blockIdx.x;
    if (bk < NB) {
        // ---- r-side ----
        int bstart = hist[bk * nblk];
        int bend = (bk + 1 < NB) ? hist[(bk + 1) * nblk] : E;
        lcnt[tid] = 0; lcnt2[tid] = 0;
        __syncthreads();
        for (int e = bstart + tid; e < bend; e += 256)
            atomicAdd(&lcnt[(rbuf[e] >> 20) & 255], 1);
        __syncthreads();
        int s = lcnt[tid];
        excl[tid] = s;
        __syncthreads();
        for (int d = 1; d < 256; d <<= 1) {
            int add = (tid >= d) ? excl[tid - d] : 0;
            __syncthreads();
            excl[tid] += add;
            __syncthreads();
        }
        int base = excl[tid] - s;   // exclusive
        excl[tid] = base;
        __syncthreads();
        int node = bk * BKT + tid;
        if (node < N) off[node] = bstart + base;
        if (bk == 0 && tid == 0) off[N] = E;
        for (int e = bstart + tid; e < bend; e += 256) {
            unsigned rec = rbuf[e];
            int rl = (rec >> 20) & 255;
            int t = (rec >> 17) & 7;
            int c = rec & 0x1FFFF;
            int pos = bstart + excl[rl] + atomicAdd(&lcnt2[rl], 1);
            edata4[pos] = (unsigned)c | ((unsigned)t << 20);
        }
    } else {
        // ---- c-side ----
        int bk2 = bk - NB;
        int NBn = NB * nblk;
        int cstart = hist[NBn + bk2 * nblk] - E;
        int cend = (bk2 + 1 < NB) ? hist[NBn + (bk2 + 1) * nblk] - E : E;
        lcnt[tid] = 0;
        __syncthreads();
        for (int e = cstart + tid; e < cend; e += 256)
            atomicAdd(&lcnt[cb8[e]], 1);
        __syncthreads();
        int node = bk2 * BKT + tid;   // covers all Np
        int d = lcnt[tid];
        dis[node] = (d > 0) ? rsqrtf((float)d) : 0.f;   // padding nodes -> 0
    }
}

// ---------------------------------------------------------------------------
// K_xy (MFMA): x = A@Win + b ; Y[r] = bf16(x)@Wrel[r].
// Yi layout [5][Np] rows of 128 ushorts: pos 2*ch = y[ch], 2*ch+1 = (x*dis)[ch].
// ---------------------------------------------------------------------------
__device__ __forceinline__ bf16x8 load_a8(const void* A, int f, size_t base) {
    if (f) {
        const float* Af = (const float*)A + base;
        bf16x8 r;
#pragma unroll
        for (int j = 0; j < 8; j++) r[j] = (short)f2bf(Af[j]);
        return r;
    }
    return *(const bf16x8*)((const unsigned short*)A + base);
}

__global__ void __launch_bounds__(256)
k_xy(const void* __restrict__ A, const void* __restrict__ binp,
     const unsigned short* __restrict__ Bpk,
     const float* __restrict__ binf, const float* __restrict__ dis,
     unsigned short* __restrict__ Yi, int N, int Np) {
    __shared__ unsigned short Bs[6 * 2 * 4 * 64 * 8];  // 48 KB
    __shared__ unsigned short Xs[64 * 64];             // 8 KB  x (frag source)
    __shared__ unsigned short Xss[64 * 64];            // 8 KB  x*dis
    __shared__ unsigned short Ys[64 * 64];             // 8 KB  y staging
    __shared__ float bs[64];
    int f = det_f32((const unsigned short*)binp);
    int tid = threadIdx.x;
    for (int i = tid; i < 6 * 2 * 4 * 64; i += 256)
        ((uint4*)Bs)[i] = ((const uint4*)Bpk)[i];
    if (tid < 64) bs[tid] = binf[tid];
    __syncthreads();

    int w = tid >> 6, lane = tid & 63;
    int q = lane >> 4, n16 = lane & 15;
    int mrow = w * 16 + n16;                  // row this lane vector-stores
    int arow = min(blockIdx.x * 64 + mrow, N - 1);
    bf16x8 a0 = load_a8(A, f, (size_t)arow * 64 + 8 * q);
    bf16x8 a1 = load_a8(A, f, (size_t)arow * 64 + 8 * q + 32);

    float disv[4];
#pragma unroll
    for (int r = 0; r < 4; r++) {
        int node = blockIdx.x * 64 + w * 16 + 4 * q + r;
        disv[r] = dis[node];                  // dis has Np entries (padding 0)
    }

    size_t snode = (size_t)(blockIdx.x * 64 + mrow);

    // stage-1: x = A @ Win + b ; Xs = x, Xss = x*dis
#pragma unroll
    for (int nt = 0; nt < 4; nt++) {
        f32x4 d = {0.f, 0.f, 0.f, 0.f};
        bf16x8 b0 = *(const bf16x8*)(Bs + (size_t)(((0 * 2 + 0) * 4 + nt) * 64 + lane) * 8);
        bf16x8 b1 = *(const bf16x8*)(Bs + (size_t)(((0 * 2 + 1) * 4 + nt) * 64 + lane) * 8);
        d = __builtin_amdgcn_mfma_f32_16x16x32_bf16(a0, b0, d, 0, 0, 0);
        d = __builtin_amdgcn_mfma_f32_16x16x32_bf16(a1, b1, d, 0, 0, 0);
        int col = nt * 16 + n16;
#pragma unroll
        for (int r = 0; r < 4; r++) {
            int rowl = w * 16 + 4 * q + r;
            float xval = d[r] + bs[col];
            Xs[rowl * 64 + col] = f2bf(xval);
            Xss[rowl * 64 + col] = f2bf(xval * disv[r]);
        }
    }
    // same-wave LDS RAW (wave w wrote only rows w*16..w*16+15) -> no barrier
    bf16x8 a20 = *(const bf16x8*)(Xs + mrow * 64 + 8 * q);
    bf16x8 a21 = *(const bf16x8*)(Xs + mrow * 64 + 8 * q + 32);

    for (int rel = 0; rel < REL; rel++) {
        int mat = 1 + rel;
#pragma unroll
        for (int nt = 0; nt < 4; nt++) {
            f32x4 d = {0.f, 0.f, 0.f, 0.f};
            bf16x8 b0 = *(const bf16x8*)(Bs + (size_t)(((mat * 2 + 0) * 4 + nt) * 64 + lane) * 8);
            bf16x8 b1 = *(const bf16x8*)(Bs + (size_t)(((mat * 2 + 1) * 4 + nt) * 64 + lane) * 8);
            d = __builtin_amdgcn_mfma_f32_16x16x32_bf16(a20, b0, d, 0, 0, 0);
            d = __builtin_amdgcn_mfma_f32_16x16x32_bf16(a21, b1, d, 0, 0, 0);
            int col = nt * 16 + n16;
#pragma unroll
            for (int r = 0; r < 4; r++)
                Ys[(w * 16 + 4 * q + r) * 64 + col] = f2bf(d[r]);
        }
        // interleave {y, x*dis} and store row mrow (4 lanes q=0..3 cover it)
        unsigned short* dst = Yi + ((size_t)rel * Np + snode) * 128;
#pragma unroll
        for (int ch = 0; ch < 2; ch++) {
            int c0 = 8 * q + 32 * ch;
            bf16x8 y8 = *(const bf16x8*)(Ys + mrow * 64 + c0);
            bf16x8 x8 = *(const bf16x8*)(Xss + mrow * 64 + c0);
            bf16x8 lo, hi;
#pragma unroll
            for (int j = 0; j < 4; j++) {
                lo[2 * j] = y8[j];     lo[2 * j + 1] = x8[j];
                hi[2 * j] = y8[4 + j]; hi[2 * j + 1] = x8[4 + j];
            }
            *(bf16x8*)(dst + 2 * c0)     = lo;
            *(bf16x8*)(dst + 2 * c0 + 8) = hi;
        }
    }
}

// ---------------------------------------------------------------------------
// K_main: one node per wave; 2 half-waves split edges; lane = 2 channels.
// 4x unroll per half (8 outstanding loads). One uint2 per edge per lane.
// ---------------------------------------------------------------------------
__global__ void __launch_bounds__(256)
k_main(const unsigned short* __restrict__ Yi, const int* __restrict__ off,
       const unsigned* __restrict__ edata4, const float* __restrict__ dis,
       unsigned short* __restrict__ v, int N, int Np) {
    int tid = threadIdx.x;
    int wv = tid >> 6, lane = tid & 63;
    int n = blockIdx.x * 4 + wv;
    if (n >= N) return;
    int half = lane >> 5;
    int co = (lane & 31) * 4;                 // ushort offset within 128-row
    int e0 = off[n], e1 = off[n + 1];
    float s0 = 0.f, s1 = 0.f, u0 = 0.f, u1 = 0.f, g0 = 0.f, g1 = 0.f;
    float s0b = 0.f, s1b = 0.f, u0b = 0.f, u1b = 0.f, g0b = 0.f, g1b = 0.f;

    int e = e0 + half;
    for (; e + 6 < e1; e += 8) {
        unsigned md[4];
#pragma unroll
        for (int j = 0; j < 4; j++) md[j] = edata4[e + 2 * j];
        uint2 y[4];
#pragma unroll
        for (int j = 0; j < 4; j++) {
            int c = md[j] & 0xFFFFF, t = md[j] >> 20;
            y[j] = *(const uint2*)(Yi + ((size_t)t * Np + c) * 128 + co);
        }
#pragma unroll
        for (int j = 0; j < 4; j++) {
            float r0 = __uint_as_float(y[j].x << 16);
            float r1 = __uint_as_float(y[j].y << 16);
            float p0 = __expf(fminf(r0, 60.f));
            float p1 = __expf(fminf(r1, 60.f));
            if (j & 1) {
                g0b += __uint_as_float(y[j].x & 0xFFFF0000u);
                g1b += __uint_as_float(y[j].y & 0xFFFF0000u);
                s0b += p0; s1b += p1;
                u0b += r0 * p0; u1b += r1 * p1;
            } else {
                g0 += __uint_as_float(y[j].x & 0xFFFF0000u);
                g1 += __uint_as_float(y[j].y & 0xFFFF0000u);
                s0 += p0; s1 += p1;
                u0 += r0 * p0; u1 += r1 * p1;
            }
        }
    }
    for (; e < e1; e += 2) {
        unsigned md = edata4[e];
        int c = md & 0xFFFFF, t = md >> 20;
        uint2 ya = *(const uint2*)(Yi + ((size_t)t * Np + c) * 128 + co);
        float r0 = __uint_as_float(ya.x << 16);
        float r1 = __uint_as_float(ya.y << 16);
        g0 += __uint_as_float(ya.x & 0xFFFF0000u);
        g1 += __uint_as_float(ya.y & 0xFFFF0000u);
        float p0 = __expf(fminf(r0, 60.f));
        float p1 = __expf(fminf(r1, 60.f));
        s0 += p0; s1 += p1;
        u0 += r0 * p0; u1 += r1 * p1;
    }
    s0 += s0b; s1 += s1b; u0 += u0b; u1 += u1b; g0 += g0b; g1 += g1b;

    s0 += __shfl_xor(s0, 32); s1 += __shfl_xor(s1, 32);
    u0 += __shfl_xor(u0, 32); u1 += __shfl_xor(u1, 32);
    g0 += __shfl_xor(g0, 32); g1 += __shfl_xor(g1, 32);
    if (half == 0) {
        float dn = dis[n];
        float m0 = u0 / (s0 + 1e-16f), m1 = u1 / (s1 + 1e-16f);
        float v0 = g0 * dn + 0.5f * fmaxf(m0, 0.f);
        float v1 = g1 * dn + 0.5f * fmaxf(m1, 0.f);
        unsigned pack = (unsigned)f2bf(v0) | ((unsigned)f2bf(v1) << 16);
        *(unsigned*)(v + (size_t)n * 64 + (lane & 31) * 2) = pack;
    }
}

// ---------------------------------------------------------------------------
// K_out (MFMA): out = v @ Wout + bout. LDS-transposed vector stores.
// ---------------------------------------------------------------------------
__global__ void __launch_bounds__(256)
k_out(const unsigned short* __restrict__ v, const void* __restrict__ binp,
      const unsigned short* __restrict__ Bpk,
      const float* __restrict__ boutf, void* __restrict__ outv, int N, int Np) {
    __shared__ unsigned short Bs[2 * 4 * 64 * 8];  // 8 KB (mat 6)
    __shared__ float Os[64 * 64];                  // 16 KB staging
    __shared__ float bs[64];
    int f = det_f32((const unsigned short*)binp);
    int tid = threadIdx.x;
    const unsigned short* src = Bpk + (size_t)6 * 2 * 4 * 64 * 8;
    for (int i = tid; i < 2 * 4 * 64; i += 256)
        ((uint4*)Bs)[i] = ((const uint4*)src)[i];
    if (tid < 64) bs[tid] = boutf[tid];
    __syncthreads();

    int w = tid >> 6, lane = tid & 63;
    int q = lane >> 4, n16 = lane & 15;
    int mrow = w * 16 + n16;
    int arow = min(blockIdx.x * 64 + mrow, N - 1);
    bf16x8 a0 = *(const bf16x8*)(v + (size_t)arow * 64 + 8 * q);
    bf16x8 a1 = *(const bf16x8*)(v + (size_t)arow * 64 + 8 * q + 32);
#pragma unroll
    for (int nt = 0; nt < 4; nt++) {
        f32x4 d = {0.f, 0.f, 0.f, 0.f};
        bf16x8 b0 = *(const bf16x8*)(Bs + (size_t)((0 * 4 + nt) * 64 + lane) * 8);
        bf16x8 b1 = *(const bf16x8*)(Bs + (size_t)((1 * 4 + nt) * 64 + lane) * 8);
        d = __builtin_amdgcn_mfma_f32_16x16x32_bf16(a0, b0, d, 0, 0, 0);
        d = __builtin_amdgcn_mfma_f32_16x16x32_bf16(a1, b1, d, 0, 0, 0);
        int col = nt * 16 + n16;
#pragma unroll
        for (int r = 0; r < 4; r++)
            Os[(w * 16 + 4 * q + r) * 64 + col] = d[r] + bs[col];
    }
    // same-wave rows -> no barrier. Vector-store row mrow.
    int node = blockIdx.x * 64 + mrow;
    if (node < N) {
        if (f) {
            float* dst = (float*)outv + (size_t)node * 64;
#pragma unroll
            for (int cchunk = 0; cchunk < 2; cchunk++) {
                int c0 = 8 * q + 32 * cchunk;
                *(f32x4*)(dst + c0)     = *(const f32x4*)(Os + mrow * 64 + c0);
                *(f32x4*)(dst + c0 + 4) = *(const f32x4*)(Os + mrow * 64 + c0 + 4);
            }
        } else {
            unsigned short* dst = (unsigned short*)outv + (size_t)node * 64;
#pragma unroll
            for (int cchunk = 0; cchunk < 2; cchunk++) {
                int c0 = 8 * q + 32 * cchunk;
                bf16x8 pk;
#pragma unroll
                for (int j = 0; j < 8; j++)
                    pk[j] = (short)f2bf(Os[mrow * 64 + c0 + j]);
                *(bf16x8*)(dst + c0) = pk;
            }
        }
    }
}

// ---------------------------------------------------------------------------
extern "C" void kernel_launch(void* const* d_in, const int* in_sizes, int n_in,
                              void* d_out, int out_size, void* d_ws, size_t ws_size,
                              hipStream_t stream) {
    const void* A    = d_in[0];
    const void* Win  = d_in[2];
    const void* bin  = d_in[3];
    const void* Wrel = d_in[4];
    const void* Wout = d_in[5];
    const void* bout = d_in[6];
    const int* ei = (const int*)d_in[7];
    const int* et = (const int*)d_in[8];
    int N = in_sizes[0] / HID;          // 50000
    int E = in_sizes[8];                // 800000
    int Np = ((N + BKT - 1) / BKT) * BKT;  // 50176 (multiple of 256 and 64)
    int NB = Np / BKT;                  // 196 buckets of 256 nodes
    int nblk = (E + EPB - 1) / EPB;     // 196 partition blocks
    int M = 2 * NB * nblk;              // concatenated hist length (~77K)
    int nsb = (M + 1023) / 1024;        // scan blocks

    char* p = (char*)d_ws;
    auto carve = [&](size_t bytes) {
        char* q = p;
        p += (bytes + 15) & ~(size_t)15;
        return q;
    };
    unsigned short* Yi   = (unsigned short*)carve((size_t)REL * Np * 128 * 2); // 64.2 MB
    unsigned short* vv   = (unsigned short*)carve((size_t)Np * 64 * 2);        // 6.4 MB
    unsigned*       rbuf = (unsigned*)carve((size_t)E * 4);                    // 3.2 MB
    unsigned char*  cb8  = (unsigned char*)carve((size_t)E);                   // 0.8 MB
    unsigned*       edata4 = (unsigned*)carve((size_t)E * 4);                  // 3.2 MB
    int*            hist = (int*)carve((size_t)M * 4);                         // 0.3 MB
    unsigned short* Bpk  = (unsigned short*)carve((size_t)7 * 4096 * 2);
    float* binf  = (float*)carve(64 * 4);
    float* boutf = (float*)carve(64 * 4);
    int* off     = (int*)carve((size_t)(N + 1) * 4);
    float* dis   = (float*)carve((size_t)Np * 4);
    int* bsum    = (int*)carve((size_t)nsb * 4);

    size_t lds_part = (size_t)2 * NB * 4;  // 1.6 KB dynamic LDS

    k_pack<<<14, 256, 0, stream>>>(Win, bin, Wrel, Wout, bout, Bpk, binf, boutf);
    k_p1a<<<nblk, 256, lds_part, stream>>>(ei, hist, E, NB, nblk);
    s_blk<<<nsb, 256, 0, stream>>>(hist, bsum, M);
    s_apply<<<nsb, 256, 0, stream>>>(hist, bsum, M, nsb);
    k_p1c<<<nblk, 256, lds_part, stream>>>(ei, et, hist, rbuf, cb8, E, NB, nblk);
    k_p2<<<2 * NB, 256, 0, stream>>>(rbuf, cb8, hist, off, edata4, dis, E, N, NB, nblk);
    k_xy<<<Np / 64, 256, 0, stream>>>(A, bin, Bpk, binf, dis, Yi, N, Np);
    k_main<<<(N + 3) / 4, 256, 0, stream>>>(Yi, off, edata4, dis, vv, N, Np);
    k_out<<<Np / 64, 256, 0, stream>>>(vv, bin, Bpk, boutf, d_out, N, Np);
}